// Round 10
// baseline (198.921 us; speedup 1.0000x reference)
//
#include <hip/hip_runtime.h>
#include <hip/hip_fp16.h>
#include <math.h>

#define NN 100000
#define NE 800000
#define HH 8
#define DD 8
#define HD 64
#define CAP 32      // padded CSR row capacity; deg ~ Poisson(8), overflow negligible (validated R3-R9)

#define NBUK 200    // dst-range buckets (500 nodes each)
#define BNODES 500
#define BCAP 4400
#define P1_EPB 1024
#define P1_BLOCKS ((NE + P1_EPB - 1) / P1_EPB)   // 782
#define P2_CHUNKS 8
#define P2_CHUNK 550

#define NOCT (NN / 8)        // 12500 octets, exact
#define AGGB (NOCT / 4)      // 3125 blocks x 4 waves

// ---------------- K0: zero deg + bucket cursors (contiguous) ----------------

__global__ void zero_kernel(int* __restrict__ p, int n) {
    int i = blockIdx.x * 256 + threadIdx.x;
    if (i < n) p[i] = 0;
}

// ---------------- pass1: bucket edges by dst range ----------------
__global__ __launch_bounds__(256) void bucket_kernel(const int* __restrict__ src,
                                                     const int* __restrict__ dst,
                                                     int* __restrict__ cursor,
                                                     int2* __restrict__ bbuf) {
    __shared__ int hist[NBUK];
    __shared__ int base[NBUK];
    const int tid = threadIdx.x;
    for (int i = tid; i < NBUK; i += 256) hist[i] = 0;
    __syncthreads();
    const int e0 = blockIdx.x * P1_EPB;
    int myb[4], myrank[4], mysrc[4], mydst[4];
#pragma unroll
    for (int i = 0; i < 4; i++) {
        int e = e0 + tid + i * 256;
        bool v = e < NE;
        int d = v ? dst[e] : 0;
        int b = d / BNODES;
        myb[i] = b;
        mydst[i] = d;
        mysrc[i] = v ? src[e] : 0;
        myrank[i] = v ? atomicAdd(&hist[b], 1) : -1;
    }
    __syncthreads();
    for (int i = tid; i < NBUK; i += 256) {
        int c = hist[i];
        base[i] = c > 0 ? atomicAdd(&cursor[i], c) : 0;
    }
    __syncthreads();
#pragma unroll
    for (int i = 0; i < 4; i++) {
        if (myrank[i] >= 0) {
            int pos = base[myb[i]] + myrank[i];
            if (pos < BCAP) bbuf[(size_t)myb[i] * BCAP + pos] = make_int2(mysrc[i], mydst[i]);
        }
    }
}

// ---------------- pass2: per-bucket scatter into padded CSR ----------------
__global__ __launch_bounds__(256) void build_kernel(const int* __restrict__ cursor,
                                                    const int2* __restrict__ bbuf,
                                                    int* __restrict__ deg,
                                                    int* __restrict__ csr_pad) {
    const int b = blockIdx.x % NBUK;
    const int chunk = blockIdx.x / NBUK;
    const int cnt = min(cursor[b], BCAP);
    const int hi = min(chunk * P2_CHUNK + P2_CHUNK, cnt);
    const int2* bb = bbuf + (size_t)b * BCAP;
    for (int i = chunk * P2_CHUNK + threadIdx.x; i < hi; i += 256) {
        int2 p = bb[i];
        int pos = atomicAdd(&deg[p.y], 1);
        if (pos < CAP) csr_pad[(size_t)p.y * CAP + pos] = p.x;
    }
}

// ---------------- lin: K-chunked LDS GEMM (unchanged) ----------------
template <int K>
__global__ __launch_bounds__(256) void lin_kernel(
    const float* __restrict__ x, const float* __restrict__ W,
    const float* __restrict__ al, const float* __restrict__ ar,
    __half* __restrict__ h, float* __restrict__ el, float* __restrict__ er) {
    __shared__ float xs[64][36];
    __shared__ float ws[32][64];
    const int tid = threadIdx.x;
    const int tx = tid & 15;
    const int ty = tid >> 4;
    const int nb = blockIdx.x * 64;

    float acc[4][4];
#pragma unroll
    for (int r = 0; r < 4; r++)
#pragma unroll
        for (int c = 0; c < 4; c++) acc[r][c] = 0.f;

    for (int kc = 0; kc < K; kc += 32) {
        __syncthreads();
#pragma unroll
        for (int it = 0; it < 2; it++) {
            int idx = tid + it * 256;
            int r = idx >> 3;
            int c4 = idx & 7;
            int node = nb + r;
            if (node >= NN) node = NN - 1;
            float4 v = *(const float4*)&x[(size_t)node * K + kc + c4 * 4];
            *(float4*)&xs[r][c4 * 4] = v;
        }
#pragma unroll
        for (int it = 0; it < 2; it++) {
            int idx = tid + it * 256;
            int wr = idx >> 4;
            int wc4 = idx & 15;
            float4 v = *(const float4*)&W[(size_t)(kc + wr) * 64 + wc4 * 4];
            *(float4*)&ws[wr][wc4 * 4] = v;
        }
        __syncthreads();
#pragma unroll
        for (int kb = 0; kb < 8; kb++) {
            float4 xv[4], wv[4];
#pragma unroll
            for (int r = 0; r < 4; r++) xv[r] = *(const float4*)&xs[4 * ty + r][kb * 4];
#pragma unroll
            for (int kk = 0; kk < 4; kk++) wv[kk] = *(const float4*)&ws[kb * 4 + kk][4 * tx];
#pragma unroll
            for (int r = 0; r < 4; r++) {
#pragma unroll
                for (int kk = 0; kk < 4; kk++) {
                    float xval = ((const float*)&xv[r])[kk];
                    acc[r][0] = fmaf(xval, wv[kk].x, acc[r][0]);
                    acc[r][1] = fmaf(xval, wv[kk].y, acc[r][1]);
                    acc[r][2] = fmaf(xval, wv[kk].z, acc[r][2]);
                    acc[r][3] = fmaf(xval, wv[kk].w, acc[r][3]);
                }
            }
        }
    }

    float alv[4], arv[4];
#pragma unroll
    for (int c = 0; c < 4; c++) { alv[c] = al[4 * tx + c]; arv[c] = ar[4 * tx + c]; }
#pragma unroll
    for (int r = 0; r < 4; r++) {
        int node = nb + 4 * ty + r;
        bool ok = node < NN;
        if (ok) {
            union { __half2 h2[2]; uint2 u; } pk;
            pk.h2[0] = __floats2half2_rn(acc[r][0], acc[r][1]);
            pk.h2[1] = __floats2half2_rn(acc[r][2], acc[r][3]);
            *(uint2*)&h[(size_t)node * HD + 4 * tx] = pk.u;
        }
        float pl = 0.f, pr = 0.f;
#pragma unroll
        for (int c = 0; c < 4; c++) {
            pl = fmaf(acc[r][c], alv[c], pl);
            pr = fmaf(acc[r][c], arv[c], pr);
        }
        pl += __shfl_xor(pl, 1);
        pr += __shfl_xor(pr, 1);
        if (ok && (tx & 1) == 0) {
            int hh = tx >> 1;
            el[node * 8 + hh] = pl;
            er[node * 8 + hh] = pr;
        }
    }
}

// ---------------- fused edge softmax + aggregation: 8 nodes/wave, head/lane ----------------
// R10: (a) registers-only CSR broadcast -- slot j of group g lives in lane
// g*8+(j>>2) component j&3; with jj%4==0 the component index is compile-time,
// so one __shfl per slot. No LDS, no __syncthreads. (b) 8-deep issue: 16
// gathers (8 el + 8 hbuf) in flight per iteration (~2 iters for cmax~14).
// Natural node order (R9): dst-side reads stay contiguous per wave.
template <bool ACT>
__global__ __launch_bounds__(256) void agg_kernel(
    const __half* __restrict__ hbuf, const float* __restrict__ el,
    const float* __restrict__ er, const int* __restrict__ deg,
    const int* __restrict__ csr_pad, const float* __restrict__ bias,
    float* __restrict__ out) {
    const int wave = threadIdx.x >> 6;
    const int lane = threadIdx.x & 63;
    const int oct = blockIdx.x * 4 + wave;   // 0..NOCT-1 exact
    const int g = lane >> 3;
    const int q = lane & 7;
    const int node = oct * 8 + g;
    const int cnt = min(deg[node], CAP);
    const float erv = er[(size_t)node * 8 + q];
    // lane (g,q) holds slots q*4..q*4+3 of group g's CSR row
    int4 rv = *(const int4*)&csr_pad[(size_t)node * CAP + q * 4];

    float4 bv0 = *(const float4*)&bias[q * 8];
    float4 bv1 = *(const float4*)&bias[q * 8 + 4];
    int cmax = cnt;
    cmax = max(cmax, __shfl_xor(cmax, 8));
    cmax = max(cmax, __shfl_xor(cmax, 16));
    cmax = max(cmax, __shfl_xor(cmax, 32));
    const int cm = max(cnt - 1, 0);
    const int gbase = lane & 56;   // g*8

    // clamp-slot src id (slot cm of own group's row), computed once
    int scl;
    {
        int bl = gbase + (cm >> 2);
        int c0 = __shfl(rv.x, bl), c1 = __shfl(rv.y, bl);
        int c2 = __shfl(rv.z, bl), c3 = __shfl(rv.w, bl);
        int cc = cm & 3;
        scl = cc == 0 ? c0 : (cc == 1 ? c1 : (cc == 2 ? c2 : c3));
        scl = (unsigned)scl < NN ? scl : 0;
    }

    float4 a0 = make_float4(0.f, 0.f, 0.f, 0.f);
    float4 a1 = make_float4(0.f, 0.f, 0.f, 0.f);
    float ssum = 0.f;

    for (int jj = 0; jj < cmax; jj += 8) {
        const int b0 = gbase + (jj >> 2);
        int sl[8];
        sl[0] = __shfl(rv.x, b0);     sl[1] = __shfl(rv.y, b0);
        sl[2] = __shfl(rv.z, b0);     sl[3] = __shfl(rv.w, b0);
        sl[4] = __shfl(rv.x, b0 + 1); sl[5] = __shfl(rv.y, b0 + 1);
        sl[6] = __shfl(rv.z, b0 + 1); sl[7] = __shfl(rv.w, b0 + 1);
        bool v[8];
#pragma unroll
        for (int t = 0; t < 8; t++) {
            v[t] = (jj + t) < cnt;
            int s = v[t] ? sl[t] : scl;          // clamp: dup rows merge/L2-hit
            sl[t] = (unsigned)s < NN ? s : 0;
        }
        float l[8];
#pragma unroll
        for (int t = 0; t < 8; t++) l[t] = el[(size_t)sl[t] * 8 + q];
        uint4 hh[8];
#pragma unroll
        for (int t = 0; t < 8; t++) hh[t] = *(const uint4*)&hbuf[(size_t)sl[t] * HD + q * 8];
#pragma unroll
        for (int t = 0; t < 8; t++) {
            float tt = l[t] + erv;
            tt = tt > 0.f ? tt : 0.2f * tt;      // leaky_relu 0.2
            float p = v[t] ? __expf(tt) : 0.f;
            ssum += p;
            float2 u0 = __half22float2(*(__half2*)&hh[t].x);
            float2 u1 = __half22float2(*(__half2*)&hh[t].y);
            float2 u2 = __half22float2(*(__half2*)&hh[t].z);
            float2 u3 = __half22float2(*(__half2*)&hh[t].w);
            a0.x = fmaf(p, u0.x, a0.x); a0.y = fmaf(p, u0.y, a0.y);
            a0.z = fmaf(p, u1.x, a0.z); a0.w = fmaf(p, u1.y, a0.w);
            a1.x = fmaf(p, u2.x, a1.x); a1.y = fmaf(p, u2.y, a1.y);
            a1.z = fmaf(p, u3.x, a1.z); a1.w = fmaf(p, u3.y, a1.w);
        }
    }

    float inv = ssum > 0.f ? 1.f / ssum : 0.f;
    float4 o0, o1;
    o0.x = fmaf(a0.x, inv, bv0.x); o0.y = fmaf(a0.y, inv, bv0.y);
    o0.z = fmaf(a0.z, inv, bv0.z); o0.w = fmaf(a0.w, inv, bv0.w);
    o1.x = fmaf(a1.x, inv, bv1.x); o1.y = fmaf(a1.y, inv, bv1.y);
    o1.z = fmaf(a1.z, inv, bv1.z); o1.w = fmaf(a1.w, inv, bv1.w);
    if (ACT) {
        o0.x = o0.x > 0.f ? o0.x : 0.01f * o0.x;
        o0.y = o0.y > 0.f ? o0.y : 0.01f * o0.y;
        o0.z = o0.z > 0.f ? o0.z : 0.01f * o0.z;
        o0.w = o0.w > 0.f ? o0.w : 0.01f * o0.w;
        o1.x = o1.x > 0.f ? o1.x : 0.01f * o1.x;
        o1.y = o1.y > 0.f ? o1.y : 0.01f * o1.y;
        o1.z = o1.z > 0.f ? o1.z : 0.01f * o1.z;
        o1.w = o1.w > 0.f ? o1.w : 0.01f * o1.w;
    }
    *(float4*)&out[(size_t)node * HD + q * 8] = o0;
    *(float4*)&out[(size_t)node * HD + q * 8 + 4] = o1;
}

// ---------------- launch ----------------

static inline size_t al512(size_t x) { return (x + 511) & ~(size_t)511; }

extern "C" void kernel_launch(void* const* d_in, const int* in_sizes, int n_in,
                              void* d_out, int out_size, void* d_ws, size_t ws_size,
                              hipStream_t stream) {
    const float* n_feat = (const float*)d_in[0];
    const int* src = (const int*)d_in[2];
    const int* dst = (const int*)d_in[3];
    const float* W[3]  = {(const float*)d_in[4], (const float*)d_in[8],  (const float*)d_in[12]};
    const float* al[3] = {(const float*)d_in[5], (const float*)d_in[9],  (const float*)d_in[13]};
    const float* ar[3] = {(const float*)d_in[6], (const float*)d_in[10], (const float*)d_in[14]};
    const float* bs[3] = {(const float*)d_in[7], (const float*)d_in[11], (const float*)d_in[15]};
    float* outF = (float*)d_out;

    char* ws = (char*)d_ws;
    size_t off = 0;
    int* deg     = (int*)(ws + off); off += (size_t)NN * 4;      // deg+cursor contiguous (zeroed together)
    int* cursor  = (int*)(ws + off); off += al512((size_t)NBUK * 4);
    int* csr_pad = (int*)(ws + off); off += al512((size_t)NN * CAP * 4);
    int2* bbuf   = (int2*)(ws + off); off += al512((size_t)NBUK * BCAP * 8);
    __half* hbuf = (__half*)(ws + off); off += al512((size_t)NN * HD * 2);
    float* el    = (float*)(ws + off); off += al512((size_t)NN * 8 * 4);
    float* er    = (float*)(ws + off); off += al512((size_t)NN * 8 * 4);

    const int ZB = (NN + NBUK + 255) / 256;
    const int LINB = (NN + 63) / 64;    // 1563

    zero_kernel<<<ZB, 256, 0, stream>>>(deg, NN + NBUK);
    bucket_kernel<<<P1_BLOCKS, 256, 0, stream>>>(src, dst, cursor, bbuf);
    build_kernel<<<NBUK * P2_CHUNKS, 256, 0, stream>>>(cursor, bbuf, deg, csr_pad);

    lin_kernel<128><<<LINB, 256, 0, stream>>>(n_feat, W[0], al[0], ar[0], hbuf, el, er);
    agg_kernel<true><<<AGGB, 256, 0, stream>>>(hbuf, el, er, deg, csr_pad, bs[0], outF);
    lin_kernel<64><<<LINB, 256, 0, stream>>>(outF, W[1], al[1], ar[1], hbuf, el, er);
    agg_kernel<true><<<AGGB, 256, 0, stream>>>(hbuf, el, er, deg, csr_pad, bs[1], outF);
    lin_kernel<64><<<LINB, 256, 0, stream>>>(outF, W[2], al[2], ar[2], hbuf, el, er);
    agg_kernel<false><<<AGGB, 256, 0, stream>>>(hbuf, el, er, deg, csr_pad, bs[2], outF);
}

// Round 11
// 174.904 us; speedup vs baseline: 1.1373x; 1.1373x over previous
//
#include <hip/hip_runtime.h>
#include <hip/hip_fp16.h>
#include <math.h>

#define NN 100000
#define NE 800000
#define HH 8
#define DD 8
#define HD 64
#define CAP 32      // padded CSR row capacity; deg ~ Poisson(8), overflow negligible (validated R3-R10)

#define NBUK 200    // dst-range buckets (500 nodes each)
#define BNODES 500
#define BCAP 4400
#define P1_EPB 1024
#define P1_BLOCKS ((NE + P1_EPB - 1) / P1_EPB)   // 782
#define P2_CHUNKS 8
#define P2_CHUNK 550

#define NOCT (NN / 8)        // 12500 octets, exact
#define AGGB (NOCT / 4)      // 3125 blocks x 4 waves

// ---------------- K0: zero deg + bucket cursors (contiguous) ----------------

__global__ void zero_kernel(int* __restrict__ p, int n) {
    int i = blockIdx.x * 256 + threadIdx.x;
    if (i < n) p[i] = 0;
}

// ---------------- pass1: bucket edges by dst range ----------------
__global__ __launch_bounds__(256) void bucket_kernel(const int* __restrict__ src,
                                                     const int* __restrict__ dst,
                                                     int* __restrict__ cursor,
                                                     int2* __restrict__ bbuf) {
    __shared__ int hist[NBUK];
    __shared__ int base[NBUK];
    const int tid = threadIdx.x;
    for (int i = tid; i < NBUK; i += 256) hist[i] = 0;
    __syncthreads();
    const int e0 = blockIdx.x * P1_EPB;
    int myb[4], myrank[4], mysrc[4], mydst[4];
#pragma unroll
    for (int i = 0; i < 4; i++) {
        int e = e0 + tid + i * 256;
        bool v = e < NE;
        int d = v ? dst[e] : 0;
        int b = d / BNODES;
        myb[i] = b;
        mydst[i] = d;
        mysrc[i] = v ? src[e] : 0;
        myrank[i] = v ? atomicAdd(&hist[b], 1) : -1;
    }
    __syncthreads();
    for (int i = tid; i < NBUK; i += 256) {
        int c = hist[i];
        base[i] = c > 0 ? atomicAdd(&cursor[i], c) : 0;
    }
    __syncthreads();
#pragma unroll
    for (int i = 0; i < 4; i++) {
        if (myrank[i] >= 0) {
            int pos = base[myb[i]] + myrank[i];
            if (pos < BCAP) bbuf[(size_t)myb[i] * BCAP + pos] = make_int2(mysrc[i], mydst[i]);
        }
    }
}

// ---------------- pass2: per-bucket scatter into padded CSR ----------------
__global__ __launch_bounds__(256) void build_kernel(const int* __restrict__ cursor,
                                                    const int2* __restrict__ bbuf,
                                                    int* __restrict__ deg,
                                                    int* __restrict__ csr_pad) {
    const int b = blockIdx.x % NBUK;
    const int chunk = blockIdx.x / NBUK;
    const int cnt = min(cursor[b], BCAP);
    const int hi = min(chunk * P2_CHUNK + P2_CHUNK, cnt);
    const int2* bb = bbuf + (size_t)b * BCAP;
    for (int i = chunk * P2_CHUNK + threadIdx.x; i < hi; i += 256) {
        int2 p = bb[i];
        int pos = atomicAdd(&deg[p.y], 1);
        if (pos < CAP) csr_pad[(size_t)p.y * CAP + pos] = p.x;
    }
}

// ---------------- lin: K-chunked LDS GEMM ----------------
// R11: el is no longer materialized (agg recomputes it from the gathered
// h row); lin emits h (fp16) + er (f32) only.
template <int K>
__global__ __launch_bounds__(256) void lin_kernel(
    const float* __restrict__ x, const float* __restrict__ W,
    const float* __restrict__ ar,
    __half* __restrict__ h, float* __restrict__ er) {
    __shared__ float xs[64][36];
    __shared__ float ws[32][64];
    const int tid = threadIdx.x;
    const int tx = tid & 15;
    const int ty = tid >> 4;
    const int nb = blockIdx.x * 64;

    float acc[4][4];
#pragma unroll
    for (int r = 0; r < 4; r++)
#pragma unroll
        for (int c = 0; c < 4; c++) acc[r][c] = 0.f;

    for (int kc = 0; kc < K; kc += 32) {
        __syncthreads();
#pragma unroll
        for (int it = 0; it < 2; it++) {
            int idx = tid + it * 256;
            int r = idx >> 3;
            int c4 = idx & 7;
            int node = nb + r;
            if (node >= NN) node = NN - 1;
            float4 v = *(const float4*)&x[(size_t)node * K + kc + c4 * 4];
            *(float4*)&xs[r][c4 * 4] = v;
        }
#pragma unroll
        for (int it = 0; it < 2; it++) {
            int idx = tid + it * 256;
            int wr = idx >> 4;
            int wc4 = idx & 15;
            float4 v = *(const float4*)&W[(size_t)(kc + wr) * 64 + wc4 * 4];
            *(float4*)&ws[wr][wc4 * 4] = v;
        }
        __syncthreads();
#pragma unroll
        for (int kb = 0; kb < 8; kb++) {
            float4 xv[4], wv[4];
#pragma unroll
            for (int r = 0; r < 4; r++) xv[r] = *(const float4*)&xs[4 * ty + r][kb * 4];
#pragma unroll
            for (int kk = 0; kk < 4; kk++) wv[kk] = *(const float4*)&ws[kb * 4 + kk][4 * tx];
#pragma unroll
            for (int r = 0; r < 4; r++) {
#pragma unroll
                for (int kk = 0; kk < 4; kk++) {
                    float xval = ((const float*)&xv[r])[kk];
                    acc[r][0] = fmaf(xval, wv[kk].x, acc[r][0]);
                    acc[r][1] = fmaf(xval, wv[kk].y, acc[r][1]);
                    acc[r][2] = fmaf(xval, wv[kk].z, acc[r][2]);
                    acc[r][3] = fmaf(xval, wv[kk].w, acc[r][3]);
                }
            }
        }
    }

    float arv[4];
#pragma unroll
    for (int c = 0; c < 4; c++) arv[c] = ar[4 * tx + c];
#pragma unroll
    for (int r = 0; r < 4; r++) {
        int node = nb + 4 * ty + r;
        bool ok = node < NN;
        if (ok) {
            union { __half2 h2[2]; uint2 u; } pk;
            pk.h2[0] = __floats2half2_rn(acc[r][0], acc[r][1]);
            pk.h2[1] = __floats2half2_rn(acc[r][2], acc[r][3]);
            *(uint2*)&h[(size_t)node * HD + 4 * tx] = pk.u;
        }
        float pr = 0.f;
#pragma unroll
        for (int c = 0; c < 4; c++) pr = fmaf(acc[r][c], arv[c], pr);
        pr += __shfl_xor(pr, 1);
        if (ok && (tx & 1) == 0) {
            int hh = tx >> 1;
            er[node * 8 + hh] = pr;
        }
    }
}

// ---------------- fused edge softmax + aggregation: 8 nodes/wave, head/lane ----------------
// R11: el computed ON THE FLY from the gathered h row (el[s][q] =
// dot(h[s][q*8..q*8+7], attn_l[q])) -- deletes the el array and 8 of 16
// gather instructions per iteration; per-edge random line demand drops from
// hbuf(128B)+el(64B line) to hbuf only. VALU had 16% busy -- 8 extra FMAs
// per edge-head are free. Natural node order (R9); register CSR broadcast
// (R10).
template <bool ACT>
__global__ __launch_bounds__(256) void agg_kernel(
    const __half* __restrict__ hbuf, const float* __restrict__ al,
    const float* __restrict__ er, const int* __restrict__ deg,
    const int* __restrict__ csr_pad, const float* __restrict__ bias,
    float* __restrict__ out) {
    const int wave = threadIdx.x >> 6;
    const int lane = threadIdx.x & 63;
    const int oct = blockIdx.x * 4 + wave;   // 0..NOCT-1 exact
    const int g = lane >> 3;
    const int q = lane & 7;
    const int node = oct * 8 + g;
    const int cnt = min(deg[node], CAP);
    const float erv = er[(size_t)node * 8 + q];
    // lane (g,q) holds slots q*4..q*4+3 of group g's CSR row
    int4 rv = *(const int4*)&csr_pad[(size_t)node * CAP + q * 4];

    float4 av0 = *(const float4*)&al[q * 8];       // attn_l[q][0..3]
    float4 av1 = *(const float4*)&al[q * 8 + 4];   // attn_l[q][4..7]
    float4 bv0 = *(const float4*)&bias[q * 8];
    float4 bv1 = *(const float4*)&bias[q * 8 + 4];
    int cmax = cnt;
    cmax = max(cmax, __shfl_xor(cmax, 8));
    cmax = max(cmax, __shfl_xor(cmax, 16));
    cmax = max(cmax, __shfl_xor(cmax, 32));
    const int cm = max(cnt - 1, 0);
    const int gbase = lane & 56;   // g*8

    // clamp-slot src id (slot cm of own group's row), computed once
    int scl;
    {
        int bl = gbase + (cm >> 2);
        int c0 = __shfl(rv.x, bl), c1 = __shfl(rv.y, bl);
        int c2 = __shfl(rv.z, bl), c3 = __shfl(rv.w, bl);
        int cc = cm & 3;
        scl = cc == 0 ? c0 : (cc == 1 ? c1 : (cc == 2 ? c2 : c3));
        scl = (unsigned)scl < NN ? scl : 0;
    }

    float4 a0 = make_float4(0.f, 0.f, 0.f, 0.f);
    float4 a1 = make_float4(0.f, 0.f, 0.f, 0.f);
    float ssum = 0.f;

    for (int jj = 0; jj < cmax; jj += 8) {
        const int b0 = gbase + (jj >> 2);
        int sl[8];
        sl[0] = __shfl(rv.x, b0);     sl[1] = __shfl(rv.y, b0);
        sl[2] = __shfl(rv.z, b0);     sl[3] = __shfl(rv.w, b0);
        sl[4] = __shfl(rv.x, b0 + 1); sl[5] = __shfl(rv.y, b0 + 1);
        sl[6] = __shfl(rv.z, b0 + 1); sl[7] = __shfl(rv.w, b0 + 1);
        bool v[8];
#pragma unroll
        for (int t = 0; t < 8; t++) {
            v[t] = (jj + t) < cnt;
            int s = v[t] ? sl[t] : scl;          // clamp: dup rows merge/L2-hit
            sl[t] = (unsigned)s < NN ? s : 0;
        }
        uint4 hh[8];
#pragma unroll
        for (int t = 0; t < 8; t++) hh[t] = *(const uint4*)&hbuf[(size_t)sl[t] * HD + q * 8];
#pragma unroll
        for (int t = 0; t < 8; t++) {
            float2 u0 = __half22float2(*(__half2*)&hh[t].x);
            float2 u1 = __half22float2(*(__half2*)&hh[t].y);
            float2 u2 = __half22float2(*(__half2*)&hh[t].z);
            float2 u3 = __half22float2(*(__half2*)&hh[t].w);
            // el on the fly: dot(h_slice, attn_l[q])
            float elv = u0.x * av0.x + u0.y * av0.y + u1.x * av0.z + u1.y * av0.w
                      + u2.x * av1.x + u2.y * av1.y + u3.x * av1.z + u3.y * av1.w;
            float tt = elv + erv;
            tt = tt > 0.f ? tt : 0.2f * tt;      // leaky_relu 0.2
            float p = v[t] ? __expf(tt) : 0.f;
            ssum += p;
            a0.x = fmaf(p, u0.x, a0.x); a0.y = fmaf(p, u0.y, a0.y);
            a0.z = fmaf(p, u1.x, a0.z); a0.w = fmaf(p, u1.y, a0.w);
            a1.x = fmaf(p, u2.x, a1.x); a1.y = fmaf(p, u2.y, a1.y);
            a1.z = fmaf(p, u3.x, a1.z); a1.w = fmaf(p, u3.y, a1.w);
        }
    }

    float inv = ssum > 0.f ? 1.f / ssum : 0.f;
    float4 o0, o1;
    o0.x = fmaf(a0.x, inv, bv0.x); o0.y = fmaf(a0.y, inv, bv0.y);
    o0.z = fmaf(a0.z, inv, bv0.z); o0.w = fmaf(a0.w, inv, bv0.w);
    o1.x = fmaf(a1.x, inv, bv1.x); o1.y = fmaf(a1.y, inv, bv1.y);
    o1.z = fmaf(a1.z, inv, bv1.z); o1.w = fmaf(a1.w, inv, bv1.w);
    if (ACT) {
        o0.x = o0.x > 0.f ? o0.x : 0.01f * o0.x;
        o0.y = o0.y > 0.f ? o0.y : 0.01f * o0.y;
        o0.z = o0.z > 0.f ? o0.z : 0.01f * o0.z;
        o0.w = o0.w > 0.f ? o0.w : 0.01f * o0.w;
        o1.x = o1.x > 0.f ? o1.x : 0.01f * o1.x;
        o1.y = o1.y > 0.f ? o1.y : 0.01f * o1.y;
        o1.z = o1.z > 0.f ? o1.z : 0.01f * o1.z;
        o1.w = o1.w > 0.f ? o1.w : 0.01f * o1.w;
    }
    *(float4*)&out[(size_t)node * HD + q * 8] = o0;
    *(float4*)&out[(size_t)node * HD + q * 8 + 4] = o1;
}

// ---------------- launch ----------------

static inline size_t al512(size_t x) { return (x + 511) & ~(size_t)511; }

extern "C" void kernel_launch(void* const* d_in, const int* in_sizes, int n_in,
                              void* d_out, int out_size, void* d_ws, size_t ws_size,
                              hipStream_t stream) {
    const float* n_feat = (const float*)d_in[0];
    const int* src = (const int*)d_in[2];
    const int* dst = (const int*)d_in[3];
    const float* W[3]  = {(const float*)d_in[4], (const float*)d_in[8],  (const float*)d_in[12]};
    const float* al[3] = {(const float*)d_in[5], (const float*)d_in[9],  (const float*)d_in[13]};
    const float* ar[3] = {(const float*)d_in[6], (const float*)d_in[10], (const float*)d_in[14]};
    const float* bs[3] = {(const float*)d_in[7], (const float*)d_in[11], (const float*)d_in[15]};
    float* outF = (float*)d_out;

    char* ws = (char*)d_ws;
    size_t off = 0;
    int* deg     = (int*)(ws + off); off += (size_t)NN * 4;      // deg+cursor contiguous (zeroed together)
    int* cursor  = (int*)(ws + off); off += al512((size_t)NBUK * 4);
    int* csr_pad = (int*)(ws + off); off += al512((size_t)NN * CAP * 4);
    int2* bbuf   = (int2*)(ws + off); off += al512((size_t)NBUK * BCAP * 8);
    __half* hbuf = (__half*)(ws + off); off += al512((size_t)NN * HD * 2);
    float* er    = (float*)(ws + off); off += al512((size_t)NN * 8 * 4);

    const int ZB = (NN + NBUK + 255) / 256;
    const int LINB = (NN + 63) / 64;    // 1563

    zero_kernel<<<ZB, 256, 0, stream>>>(deg, NN + NBUK);
    bucket_kernel<<<P1_BLOCKS, 256, 0, stream>>>(src, dst, cursor, bbuf);
    build_kernel<<<NBUK * P2_CHUNKS, 256, 0, stream>>>(cursor, bbuf, deg, csr_pad);

    lin_kernel<128><<<LINB, 256, 0, stream>>>(n_feat, W[0], ar[0], hbuf, er);
    agg_kernel<true><<<AGGB, 256, 0, stream>>>(hbuf, al[0], er, deg, csr_pad, bs[0], outF);
    lin_kernel<64><<<LINB, 256, 0, stream>>>(outF, W[1], ar[1], hbuf, er);
    agg_kernel<true><<<AGGB, 256, 0, stream>>>(hbuf, al[1], er, deg, csr_pad, bs[1], outF);
    lin_kernel<64><<<LINB, 256, 0, stream>>>(outF, W[2], ar[2], hbuf, er);
    agg_kernel<false><<<AGGB, 256, 0, stream>>>(hbuf, al[2], er, deg, csr_pad, bs[2], outF);
}

// Round 12
// 165.496 us; speedup vs baseline: 1.2020x; 1.0568x over previous
//
#include <hip/hip_runtime.h>
#include <hip/hip_fp16.h>
#include <math.h>

#define NN 100000
#define NE 800000
#define HH 8
#define DD 8
#define HD 64
#define CAP 32      // padded CSR row capacity; deg ~ Poisson(8), overflow negligible (validated R3-R11)

#define NBUK 200    // dst-range buckets (500 nodes each)
#define BNODES 500
#define BCAP 4400
#define P1_EPB 1024
#define P1_BLOCKS ((NE + P1_EPB - 1) / P1_EPB)   // 782
#define P2_CHUNKS 8
#define P2_CHUNK 550

#define NOCT (NN / 8)        // 12500 octets, exact
#define AGGB (NOCT / 4)      // 3125 blocks x 4 waves
#define LINB ((NN + 63) / 64)

typedef _Float16 half8_t __attribute__((ext_vector_type(8)));
typedef float f32x4_t __attribute__((ext_vector_type(4)));

// ---------------- K0: zero deg + bucket cursors (contiguous) ----------------

__global__ void zero_kernel(int* __restrict__ p, int n) {
    int i = blockIdx.x * 256 + threadIdx.x;
    if (i < n) p[i] = 0;
}

// ---------------- pass1: bucket edges by dst range ----------------
__global__ __launch_bounds__(256) void bucket_kernel(const int* __restrict__ src,
                                                     const int* __restrict__ dst,
                                                     int* __restrict__ cursor,
                                                     int2* __restrict__ bbuf) {
    __shared__ int hist[NBUK];
    __shared__ int base[NBUK];
    const int tid = threadIdx.x;
    for (int i = tid; i < NBUK; i += 256) hist[i] = 0;
    __syncthreads();
    const int e0 = blockIdx.x * P1_EPB;
    int myb[4], myrank[4], mysrc[4], mydst[4];
#pragma unroll
    for (int i = 0; i < 4; i++) {
        int e = e0 + tid + i * 256;
        bool v = e < NE;
        int d = v ? dst[e] : 0;
        int b = d / BNODES;
        myb[i] = b;
        mydst[i] = d;
        mysrc[i] = v ? src[e] : 0;
        myrank[i] = v ? atomicAdd(&hist[b], 1) : -1;
    }
    __syncthreads();
    for (int i = tid; i < NBUK; i += 256) {
        int c = hist[i];
        base[i] = c > 0 ? atomicAdd(&cursor[i], c) : 0;
    }
    __syncthreads();
#pragma unroll
    for (int i = 0; i < 4; i++) {
        if (myrank[i] >= 0) {
            int pos = base[myb[i]] + myrank[i];
            if (pos < BCAP) bbuf[(size_t)myb[i] * BCAP + pos] = make_int2(mysrc[i], mydst[i]);
        }
    }
}

// ---------------- pass2: per-bucket scatter into padded CSR ----------------
__global__ __launch_bounds__(256) void build_kernel(const int* __restrict__ cursor,
                                                    const int2* __restrict__ bbuf,
                                                    int* __restrict__ deg,
                                                    int* __restrict__ csr_pad) {
    const int b = blockIdx.x % NBUK;
    const int chunk = blockIdx.x / NBUK;
    const int cnt = min(cursor[b], BCAP);
    const int hi = min(chunk * P2_CHUNK + P2_CHUNK, cnt);
    const int2* bb = bbuf + (size_t)b * BCAP;
    for (int i = chunk * P2_CHUNK + threadIdx.x; i < hi; i += 256) {
        int2 p = bb[i];
        int pos = atomicAdd(&deg[p.y], 1);
        if (pos < CAP) csr_pad[(size_t)p.y * CAP + pos] = p.x;
    }
}

// ---------------- lin: MFMA fp16 GEMM ----------------
// h[N,64] = x[N,K] @ W[K,64] via mfma_f32_16x16x32_f16.
// Block = 64 rows x 64 cols, 4 waves; wave w owns cols w*16..w*16+15,
// iterating 4 row-tiles x K/32 k-steps (bfrag reused across row-tiles).
// LDS: x as fp16 [64][K+8] (pad -> 16B-aligned rows, 2-way bank alias = free);
// W TRANSPOSED [64][K+8] so both fragments are contiguous ds_read_b128:
//   A: lane l -> x[row=l&15][k=(l>>4)*8+j]; B: lane l -> W^T[col=l&15][same k].
// C/D layout (m89): col=lane&15, row=(lane>>4)*4+reg.
// Epilogue: h fp16 store + er via 3x shfl_xor over the 8 cols of each head.
template <int K, typename IT>
__global__ __launch_bounds__(256) void lin_mfma(
    const IT* __restrict__ x, const float* __restrict__ W,
    const float* __restrict__ ar,
    __half* __restrict__ h, float* __restrict__ er) {
    constexpr int KP = K + 8;
    __shared__ _Float16 xh[64][KP];
    __shared__ _Float16 wt[64][KP];
    const int tid = threadIdx.x;
    const int w = tid >> 6;
    const int l = tid & 63;
    const int nb = blockIdx.x * 64;

    // stage x -> fp16 LDS
    if constexpr (sizeof(IT) == 4) {
        constexpr int NIT = (64 * K / 4) / 256;    // 8 (K=128) / 4 (K=64)
#pragma unroll
        for (int it = 0; it < NIT; it++) {
            int idx = tid + it * 256;
            int r = idx / (K / 4);
            int c4 = idx % (K / 4);
            int node = nb + r; if (node >= NN) node = NN - 1;
            float4 v = *(const float4*)&x[(size_t)node * K + c4 * 4];
            union { _Float16 f[4]; uint2 u; } pk;
            pk.f[0] = (_Float16)v.x; pk.f[1] = (_Float16)v.y;
            pk.f[2] = (_Float16)v.z; pk.f[3] = (_Float16)v.w;
            *(uint2*)&xh[r][c4 * 4] = pk.u;
        }
    } else {
        constexpr int NIT = (64 * K / 8) / 256;    // 2 (K=64)
#pragma unroll
        for (int it = 0; it < NIT; it++) {
            int idx = tid + it * 256;
            int r = idx / (K / 8);
            int u8 = idx % (K / 8);
            int node = nb + r; if (node >= NN) node = NN - 1;
            uint4 v = *(const uint4*)&x[(size_t)node * K + u8 * 8];
            *(uint4*)&xh[r][u8 * 8] = v;
        }
    }
    // stage W transposed -> fp16 LDS
    {
        constexpr int NIT = (K * 64 / 4) / 256;    // 8 (K=128) / 4 (K=64)
#pragma unroll
        for (int it = 0; it < NIT; it++) {
            int idx = tid + it * 256;
            int k = idx >> 4;
            int c0 = (idx & 15) * 4;
            float4 v = *(const float4*)&W[(size_t)k * 64 + c0];
            wt[c0][k]     = (_Float16)v.x;
            wt[c0 + 1][k] = (_Float16)v.y;
            wt[c0 + 2][k] = (_Float16)v.z;
            wt[c0 + 3][k] = (_Float16)v.w;
        }
    }
    __syncthreads();

    const int row16 = l & 15;
    const int kgrp = (l >> 4) * 8;
    f32x4_t acc[4];
#pragma unroll
    for (int r = 0; r < 4; r++) acc[r] = (f32x4_t){0.f, 0.f, 0.f, 0.f};

#pragma unroll
    for (int k0 = 0; k0 < K; k0 += 32) {
        half8_t bf = *(const half8_t*)&wt[w * 16 + row16][k0 + kgrp];
#pragma unroll
        for (int r = 0; r < 4; r++) {
            half8_t af = *(const half8_t*)&xh[r * 16 + row16][k0 + kgrp];
            acc[r] = __builtin_amdgcn_mfma_f32_16x16x32_f16(af, bf, acc[r], 0, 0, 0);
        }
    }

    const int colw = w * 16 + row16;
    const float arc = ar[colw];
    const int rg = (l >> 4) * 4;
    const int head = colw >> 3;
#pragma unroll
    for (int r = 0; r < 4; r++) {
#pragma unroll
        for (int j = 0; j < 4; j++) {
            int node = nb + r * 16 + rg + j;
            float val = acc[r][j];
            if (node < NN) h[(size_t)node * HD + colw] = __float2half(val);
            float p = val * arc;
            p += __shfl_xor(p, 1);
            p += __shfl_xor(p, 2);
            p += __shfl_xor(p, 4);
            if ((l & 7) == 0 && node < NN) er[(size_t)node * 8 + head] = p;
        }
    }
}

// ---------------- fused edge softmax + aggregation (R11 structure) ----------------
// HOUT: write fp16 (next layer's GEMM input) or f32 (final output).
template <bool ACT, bool HOUT>
__global__ __launch_bounds__(256) void agg_kernel(
    const __half* __restrict__ hbuf, const float* __restrict__ al,
    const float* __restrict__ er, const int* __restrict__ deg,
    const int* __restrict__ csr_pad, const float* __restrict__ bias,
    void* __restrict__ outv) {
    const int wave = threadIdx.x >> 6;
    const int lane = threadIdx.x & 63;
    const int oct = blockIdx.x * 4 + wave;   // 0..NOCT-1 exact
    const int g = lane >> 3;
    const int q = lane & 7;
    const int node = oct * 8 + g;
    const int cnt = min(deg[node], CAP);
    const float erv = er[(size_t)node * 8 + q];
    int4 rv = *(const int4*)&csr_pad[(size_t)node * CAP + q * 4];

    float4 av0 = *(const float4*)&al[q * 8];
    float4 av1 = *(const float4*)&al[q * 8 + 4];
    float4 bv0 = *(const float4*)&bias[q * 8];
    float4 bv1 = *(const float4*)&bias[q * 8 + 4];
    int cmax = cnt;
    cmax = max(cmax, __shfl_xor(cmax, 8));
    cmax = max(cmax, __shfl_xor(cmax, 16));
    cmax = max(cmax, __shfl_xor(cmax, 32));
    const int cm = max(cnt - 1, 0);
    const int gbase = lane & 56;   // g*8

    int scl;
    {
        int bl = gbase + (cm >> 2);
        int c0 = __shfl(rv.x, bl), c1 = __shfl(rv.y, bl);
        int c2 = __shfl(rv.z, bl), c3 = __shfl(rv.w, bl);
        int cc = cm & 3;
        scl = cc == 0 ? c0 : (cc == 1 ? c1 : (cc == 2 ? c2 : c3));
        scl = (unsigned)scl < NN ? scl : 0;
    }

    float4 a0 = make_float4(0.f, 0.f, 0.f, 0.f);
    float4 a1 = make_float4(0.f, 0.f, 0.f, 0.f);
    float ssum = 0.f;

    for (int jj = 0; jj < cmax; jj += 8) {
        const int b0 = gbase + (jj >> 2);
        int sl[8];
        sl[0] = __shfl(rv.x, b0);     sl[1] = __shfl(rv.y, b0);
        sl[2] = __shfl(rv.z, b0);     sl[3] = __shfl(rv.w, b0);
        sl[4] = __shfl(rv.x, b0 + 1); sl[5] = __shfl(rv.y, b0 + 1);
        sl[6] = __shfl(rv.z, b0 + 1); sl[7] = __shfl(rv.w, b0 + 1);
        bool v[8];
#pragma unroll
        for (int t = 0; t < 8; t++) {
            v[t] = (jj + t) < cnt;
            int s = v[t] ? sl[t] : scl;
            sl[t] = (unsigned)s < NN ? s : 0;
        }
        uint4 hh[8];
#pragma unroll
        for (int t = 0; t < 8; t++) hh[t] = *(const uint4*)&hbuf[(size_t)sl[t] * HD + q * 8];
#pragma unroll
        for (int t = 0; t < 8; t++) {
            float2 u0 = __half22float2(*(__half2*)&hh[t].x);
            float2 u1 = __half22float2(*(__half2*)&hh[t].y);
            float2 u2 = __half22float2(*(__half2*)&hh[t].z);
            float2 u3 = __half22float2(*(__half2*)&hh[t].w);
            float elv = u0.x * av0.x + u0.y * av0.y + u1.x * av0.z + u1.y * av0.w
                      + u2.x * av1.x + u2.y * av1.y + u3.x * av1.z + u3.y * av1.w;
            float tt = elv + erv;
            tt = tt > 0.f ? tt : 0.2f * tt;
            float p = v[t] ? __expf(tt) : 0.f;
            ssum += p;
            a0.x = fmaf(p, u0.x, a0.x); a0.y = fmaf(p, u0.y, a0.y);
            a0.z = fmaf(p, u1.x, a0.z); a0.w = fmaf(p, u1.y, a0.w);
            a1.x = fmaf(p, u2.x, a1.x); a1.y = fmaf(p, u2.y, a1.y);
            a1.z = fmaf(p, u3.x, a1.z); a1.w = fmaf(p, u3.y, a1.w);
        }
    }

    float inv = ssum > 0.f ? 1.f / ssum : 0.f;
    float4 o0, o1;
    o0.x = fmaf(a0.x, inv, bv0.x); o0.y = fmaf(a0.y, inv, bv0.y);
    o0.z = fmaf(a0.z, inv, bv0.z); o0.w = fmaf(a0.w, inv, bv0.w);
    o1.x = fmaf(a1.x, inv, bv1.x); o1.y = fmaf(a1.y, inv, bv1.y);
    o1.z = fmaf(a1.z, inv, bv1.z); o1.w = fmaf(a1.w, inv, bv1.w);
    if (ACT) {
        o0.x = o0.x > 0.f ? o0.x : 0.01f * o0.x;
        o0.y = o0.y > 0.f ? o0.y : 0.01f * o0.y;
        o0.z = o0.z > 0.f ? o0.z : 0.01f * o0.z;
        o0.w = o0.w > 0.f ? o0.w : 0.01f * o0.w;
        o1.x = o1.x > 0.f ? o1.x : 0.01f * o1.x;
        o1.y = o1.y > 0.f ? o1.y : 0.01f * o1.y;
        o1.z = o1.z > 0.f ? o1.z : 0.01f * o1.z;
        o1.w = o1.w > 0.f ? o1.w : 0.01f * o1.w;
    }
    if constexpr (HOUT) {
        __half* o = (__half*)outv;
        union { __half2 h2[4]; uint4 u; } pk;
        pk.h2[0] = __floats2half2_rn(o0.x, o0.y);
        pk.h2[1] = __floats2half2_rn(o0.z, o0.w);
        pk.h2[2] = __floats2half2_rn(o1.x, o1.y);
        pk.h2[3] = __floats2half2_rn(o1.z, o1.w);
        *(uint4*)&o[(size_t)node * HD + q * 8] = pk.u;
    } else {
        float* o = (float*)outv;
        *(float4*)&o[(size_t)node * HD + q * 8] = o0;
        *(float4*)&o[(size_t)node * HD + q * 8 + 4] = o1;
    }
}

// ---------------- launch ----------------

static inline size_t al512(size_t x) { return (x + 511) & ~(size_t)511; }

extern "C" void kernel_launch(void* const* d_in, const int* in_sizes, int n_in,
                              void* d_out, int out_size, void* d_ws, size_t ws_size,
                              hipStream_t stream) {
    const float* n_feat = (const float*)d_in[0];
    const int* src = (const int*)d_in[2];
    const int* dst = (const int*)d_in[3];
    const float* W[3]  = {(const float*)d_in[4], (const float*)d_in[8],  (const float*)d_in[12]};
    const float* al[3] = {(const float*)d_in[5], (const float*)d_in[9],  (const float*)d_in[13]};
    const float* ar[3] = {(const float*)d_in[6], (const float*)d_in[10], (const float*)d_in[14]};
    const float* bs[3] = {(const float*)d_in[7], (const float*)d_in[11], (const float*)d_in[15]};
    float* outF = (float*)d_out;

    char* ws = (char*)d_ws;
    size_t off = 0;
    int* deg     = (int*)(ws + off); off += (size_t)NN * 4;      // deg+cursor contiguous (zeroed together)
    int* cursor  = (int*)(ws + off); off += al512((size_t)NBUK * 4);
    int* csr_pad = (int*)(ws + off); off += al512((size_t)NN * CAP * 4);
    int2* bbuf   = (int2*)(ws + off); off += al512((size_t)NBUK * BCAP * 8);
    __half* hbuf = (__half*)(ws + off); off += al512((size_t)NN * HD * 2);
    __half* xh   = (__half*)(ws + off); off += al512((size_t)NN * HD * 2);
    float* er    = (float*)(ws + off); off += al512((size_t)NN * 8 * 4);

    const int ZB = (NN + NBUK + 255) / 256;

    zero_kernel<<<ZB, 256, 0, stream>>>(deg, NN + NBUK);
    bucket_kernel<<<P1_BLOCKS, 256, 0, stream>>>(src, dst, cursor, bbuf);
    build_kernel<<<NBUK * P2_CHUNKS, 256, 0, stream>>>(cursor, bbuf, deg, csr_pad);

    lin_mfma<128, float><<<LINB, 256, 0, stream>>>(n_feat, W[0], ar[0], hbuf, er);
    agg_kernel<true, true><<<AGGB, 256, 0, stream>>>(hbuf, al[0], er, deg, csr_pad, bs[0], xh);
    lin_mfma<64, __half><<<LINB, 256, 0, stream>>>(xh, W[1], ar[1], hbuf, er);
    agg_kernel<true, true><<<AGGB, 256, 0, stream>>>(hbuf, al[1], er, deg, csr_pad, bs[1], xh);
    lin_mfma<64, __half><<<LINB, 256, 0, stream>>>(xh, W[2], ar[2], hbuf, er);
    agg_kernel<false, false><<<AGGB, 256, 0, stream>>>(hbuf, al[2], er, deg, csr_pad, bs[2], outF);
}

// Round 13
// 151.830 us; speedup vs baseline: 1.3102x; 1.0900x over previous
//
#include <hip/hip_runtime.h>
#include <hip/hip_fp16.h>
#include <math.h>

#define NN 100000
#define NE 800000
#define HH 8
#define DD 8
#define HD 64
#define CAP 32      // padded CSR row capacity; deg ~ Poisson(8), overflow negligible (validated R3-R12)

#define NBUK 200    // dst-range buckets (500 nodes each)
#define BNODES 500
#define BCAP 4400
#define P1_EPB 1024
#define P1_BLOCKS ((NE + P1_EPB - 1) / P1_EPB)   // 782
#define P2_CHUNKS 8
#define P2_CHUNK 550

#define NOCT (NN / 8)        // 12500 octets, exact
#define AGGB (NOCT / 4)      // 3125 blocks x 4 waves (32 nodes/block)
#define LINB ((NN + 63) / 64)

typedef _Float16 half8_t __attribute__((ext_vector_type(8)));
typedef float f32x4_t __attribute__((ext_vector_type(4)));

// ---------------- K0: zero deg + bucket cursors (contiguous) ----------------

__global__ void zero_kernel(int* __restrict__ p, int n) {
    int i = blockIdx.x * 256 + threadIdx.x;
    if (i < n) p[i] = 0;
}

// ---------------- pass1: bucket edges by dst range ----------------
__global__ __launch_bounds__(256) void bucket_kernel(const int* __restrict__ src,
                                                     const int* __restrict__ dst,
                                                     int* __restrict__ cursor,
                                                     int2* __restrict__ bbuf) {
    __shared__ int hist[NBUK];
    __shared__ int base[NBUK];
    const int tid = threadIdx.x;
    for (int i = tid; i < NBUK; i += 256) hist[i] = 0;
    __syncthreads();
    const int e0 = blockIdx.x * P1_EPB;
    int myb[4], myrank[4], mysrc[4], mydst[4];
#pragma unroll
    for (int i = 0; i < 4; i++) {
        int e = e0 + tid + i * 256;
        bool v = e < NE;
        int d = v ? dst[e] : 0;
        int b = d / BNODES;
        myb[i] = b;
        mydst[i] = d;
        mysrc[i] = v ? src[e] : 0;
        myrank[i] = v ? atomicAdd(&hist[b], 1) : -1;
    }
    __syncthreads();
    for (int i = tid; i < NBUK; i += 256) {
        int c = hist[i];
        base[i] = c > 0 ? atomicAdd(&cursor[i], c) : 0;
    }
    __syncthreads();
#pragma unroll
    for (int i = 0; i < 4; i++) {
        if (myrank[i] >= 0) {
            int pos = base[myb[i]] + myrank[i];
            if (pos < BCAP) bbuf[(size_t)myb[i] * BCAP + pos] = make_int2(mysrc[i], mydst[i]);
        }
    }
}

// ---------------- pass2: per-bucket scatter into padded CSR ----------------
__global__ __launch_bounds__(256) void build_kernel(const int* __restrict__ cursor,
                                                    const int2* __restrict__ bbuf,
                                                    int* __restrict__ deg,
                                                    int* __restrict__ csr_pad) {
    const int b = blockIdx.x % NBUK;
    const int chunk = blockIdx.x / NBUK;
    const int cnt = min(cursor[b], BCAP);
    const int hi = min(chunk * P2_CHUNK + P2_CHUNK, cnt);
    const int2* bb = bbuf + (size_t)b * BCAP;
    for (int i = chunk * P2_CHUNK + threadIdx.x; i < hi; i += 256) {
        int2 p = bb[i];
        int pos = atomicAdd(&deg[p.y], 1);
        if (pos < CAP) csr_pad[(size_t)p.y * CAP + pos] = p.x;
    }
}

// ---------------- lin0: MFMA fp16 GEMM (layer 0 only, K=128, f32 input) ----------------
__global__ __launch_bounds__(256) void lin_mfma(
    const float* __restrict__ x, const float* __restrict__ W,
    const float* __restrict__ ar,
    __half* __restrict__ h, float* __restrict__ er) {
    constexpr int K = 128, KP = K + 8;
    __shared__ _Float16 xh[64][KP];
    __shared__ _Float16 wt[64][KP];
    const int tid = threadIdx.x;
    const int w = tid >> 6;
    const int l = tid & 63;
    const int nb = blockIdx.x * 64;

#pragma unroll
    for (int it = 0; it < 8; it++) {
        int idx = tid + it * 256;
        int r = idx / (K / 4);
        int c4 = idx % (K / 4);
        int node = nb + r; if (node >= NN) node = NN - 1;
        float4 v = *(const float4*)&x[(size_t)node * K + c4 * 4];
        union { _Float16 f[4]; uint2 u; } pk;
        pk.f[0] = (_Float16)v.x; pk.f[1] = (_Float16)v.y;
        pk.f[2] = (_Float16)v.z; pk.f[3] = (_Float16)v.w;
        *(uint2*)&xh[r][c4 * 4] = pk.u;
    }
#pragma unroll
    for (int it = 0; it < 8; it++) {
        int idx = tid + it * 256;
        int k = idx >> 4;
        int c0 = (idx & 15) * 4;
        float4 v = *(const float4*)&W[(size_t)k * 64 + c0];
        wt[c0][k]     = (_Float16)v.x;
        wt[c0 + 1][k] = (_Float16)v.y;
        wt[c0 + 2][k] = (_Float16)v.z;
        wt[c0 + 3][k] = (_Float16)v.w;
    }
    __syncthreads();

    const int row16 = l & 15;
    const int kgrp = (l >> 4) * 8;
    f32x4_t acc[4];
#pragma unroll
    for (int r = 0; r < 4; r++) acc[r] = (f32x4_t){0.f, 0.f, 0.f, 0.f};

#pragma unroll
    for (int k0 = 0; k0 < K; k0 += 32) {
        half8_t bf = *(const half8_t*)&wt[w * 16 + row16][k0 + kgrp];
#pragma unroll
        for (int r = 0; r < 4; r++) {
            half8_t af = *(const half8_t*)&xh[r * 16 + row16][k0 + kgrp];
            acc[r] = __builtin_amdgcn_mfma_f32_16x16x32_f16(af, bf, acc[r], 0, 0, 0);
        }
    }

    const int colw = w * 16 + row16;
    const float arc = ar[colw];
    const int rg = (l >> 4) * 4;
    const int head = colw >> 3;
#pragma unroll
    for (int r = 0; r < 4; r++) {
#pragma unroll
        for (int j = 0; j < 4; j++) {
            int node = nb + r * 16 + rg + j;
            float val = acc[r][j];
            if (node < NN) h[(size_t)node * HD + colw] = __float2half(val);
            float p = val * arc;
            p += __shfl_xor(p, 1);
            p += __shfl_xor(p, 2);
            p += __shfl_xor(p, 4);
            if ((l & 7) == 0 && node < NN) er[(size_t)node * 8 + head] = p;
        }
    }
}

// ---------------- fused agg + next-layer lin ----------------
// Per block: 4 waves x 8 nodes = 32 nodes. Phase 1 = R11 agg (el on the fly,
// register CSR broadcast). Output rows (post-bias/act) go to LDS as fp16 --
// they are ONLY needed as next layer's GEMM input (no global round-trip).
// Phase 2 = 32x64x64 MFMA GEMM vs W_next (fp16^T staged in LDS at start,
// L2-broadcast), h' fp16 + er' to the double-buffered outputs.
template <bool ACT>
__global__ __launch_bounds__(256) void agg_lin_kernel(
    const __half* __restrict__ hbuf_in, const float* __restrict__ al,
    const float* __restrict__ er_in, const int* __restrict__ deg,
    const int* __restrict__ csr_pad, const float* __restrict__ bias,
    const float* __restrict__ Wn, const float* __restrict__ arn,
    __half* __restrict__ hbuf_out, float* __restrict__ er_out) {
    __shared__ _Float16 wt[64][72];   // W_next transposed, fp16
    __shared__ _Float16 xs[32][72];   // this block's 32 output rows, fp16
    const int tid = threadIdx.x;
    const int wave = tid >> 6;
    const int lane = tid & 63;
    const int oct = blockIdx.x * 4 + wave;
    const int g = lane >> 3;
    const int q = lane & 7;
    const int node = oct * 8 + g;

    // stage W_next^T (16KB f32 read, L2-resident broadcast)
#pragma unroll
    for (int it = 0; it < 4; it++) {
        int idx = tid + it * 256;
        int k = idx >> 4;
        int c0 = (idx & 15) * 4;
        float4 v = *(const float4*)&Wn[(size_t)k * 64 + c0];
        wt[c0][k]     = (_Float16)v.x;
        wt[c0 + 1][k] = (_Float16)v.y;
        wt[c0 + 2][k] = (_Float16)v.z;
        wt[c0 + 3][k] = (_Float16)v.w;
    }

    const int cnt = min(deg[node], CAP);
    const float erv = er_in[(size_t)node * 8 + q];
    int4 rv = *(const int4*)&csr_pad[(size_t)node * CAP + q * 4];

    float4 av0 = *(const float4*)&al[q * 8];
    float4 av1 = *(const float4*)&al[q * 8 + 4];
    float4 bv0 = *(const float4*)&bias[q * 8];
    float4 bv1 = *(const float4*)&bias[q * 8 + 4];
    int cmax = cnt;
    cmax = max(cmax, __shfl_xor(cmax, 8));
    cmax = max(cmax, __shfl_xor(cmax, 16));
    cmax = max(cmax, __shfl_xor(cmax, 32));
    const int cm = max(cnt - 1, 0);
    const int gbase = lane & 56;

    int scl;
    {
        int bl = gbase + (cm >> 2);
        int c0 = __shfl(rv.x, bl), c1 = __shfl(rv.y, bl);
        int c2 = __shfl(rv.z, bl), c3 = __shfl(rv.w, bl);
        int cc = cm & 3;
        scl = cc == 0 ? c0 : (cc == 1 ? c1 : (cc == 2 ? c2 : c3));
        scl = (unsigned)scl < NN ? scl : 0;
    }

    float4 a0 = make_float4(0.f, 0.f, 0.f, 0.f);
    float4 a1 = make_float4(0.f, 0.f, 0.f, 0.f);
    float ssum = 0.f;

    for (int jj = 0; jj < cmax; jj += 8) {
        const int b0 = gbase + (jj >> 2);
        int sl[8];
        sl[0] = __shfl(rv.x, b0);     sl[1] = __shfl(rv.y, b0);
        sl[2] = __shfl(rv.z, b0);     sl[3] = __shfl(rv.w, b0);
        sl[4] = __shfl(rv.x, b0 + 1); sl[5] = __shfl(rv.y, b0 + 1);
        sl[6] = __shfl(rv.z, b0 + 1); sl[7] = __shfl(rv.w, b0 + 1);
        bool v[8];
#pragma unroll
        for (int t = 0; t < 8; t++) {
            v[t] = (jj + t) < cnt;
            int s = v[t] ? sl[t] : scl;
            sl[t] = (unsigned)s < NN ? s : 0;
        }
        uint4 hh[8];
#pragma unroll
        for (int t = 0; t < 8; t++) hh[t] = *(const uint4*)&hbuf_in[(size_t)sl[t] * HD + q * 8];
#pragma unroll
        for (int t = 0; t < 8; t++) {
            float2 u0 = __half22float2(*(__half2*)&hh[t].x);
            float2 u1 = __half22float2(*(__half2*)&hh[t].y);
            float2 u2 = __half22float2(*(__half2*)&hh[t].z);
            float2 u3 = __half22float2(*(__half2*)&hh[t].w);
            float elv = u0.x * av0.x + u0.y * av0.y + u1.x * av0.z + u1.y * av0.w
                      + u2.x * av1.x + u2.y * av1.y + u3.x * av1.z + u3.y * av1.w;
            float tt = elv + erv;
            tt = tt > 0.f ? tt : 0.2f * tt;
            float p = v[t] ? __expf(tt) : 0.f;
            ssum += p;
            a0.x = fmaf(p, u0.x, a0.x); a0.y = fmaf(p, u0.y, a0.y);
            a0.z = fmaf(p, u1.x, a0.z); a0.w = fmaf(p, u1.y, a0.w);
            a1.x = fmaf(p, u2.x, a1.x); a1.y = fmaf(p, u2.y, a1.y);
            a1.z = fmaf(p, u3.x, a1.z); a1.w = fmaf(p, u3.y, a1.w);
        }
    }

    float inv = ssum > 0.f ? 1.f / ssum : 0.f;
    float o0x = fmaf(a0.x, inv, bv0.x), o0y = fmaf(a0.y, inv, bv0.y);
    float o0z = fmaf(a0.z, inv, bv0.z), o0w = fmaf(a0.w, inv, bv0.w);
    float o1x = fmaf(a1.x, inv, bv1.x), o1y = fmaf(a1.y, inv, bv1.y);
    float o1z = fmaf(a1.z, inv, bv1.z), o1w = fmaf(a1.w, inv, bv1.w);
    if (ACT) {
        o0x = o0x > 0.f ? o0x : 0.01f * o0x;
        o0y = o0y > 0.f ? o0y : 0.01f * o0y;
        o0z = o0z > 0.f ? o0z : 0.01f * o0z;
        o0w = o0w > 0.f ? o0w : 0.01f * o0w;
        o1x = o1x > 0.f ? o1x : 0.01f * o1x;
        o1y = o1y > 0.f ? o1y : 0.01f * o1y;
        o1z = o1z > 0.f ? o1z : 0.01f * o1z;
        o1w = o1w > 0.f ? o1w : 0.01f * o1w;
    }
    // output row -> LDS fp16 (input of the fused next-layer GEMM)
    {
        union { _Float16 f[8]; uint4 u; } pk;
        pk.f[0] = (_Float16)o0x; pk.f[1] = (_Float16)o0y;
        pk.f[2] = (_Float16)o0z; pk.f[3] = (_Float16)o0w;
        pk.f[4] = (_Float16)o1x; pk.f[5] = (_Float16)o1y;
        pk.f[6] = (_Float16)o1z; pk.f[7] = (_Float16)o1w;
        *(uint4*)&xs[wave * 8 + g][q * 8] = pk.u;
    }
    __syncthreads();

    // phase 2: 32x64x64 MFMA -- wave w owns cols w*16..+15, 2 M-tiles, K=64
    const int row16 = lane & 15;
    const int kgrp = (lane >> 4) * 8;
    f32x4_t acc[2];
    acc[0] = (f32x4_t){0.f, 0.f, 0.f, 0.f};
    acc[1] = (f32x4_t){0.f, 0.f, 0.f, 0.f};
#pragma unroll
    for (int k0 = 0; k0 < 64; k0 += 32) {
        half8_t bf = *(const half8_t*)&wt[wave * 16 + row16][k0 + kgrp];
#pragma unroll
        for (int mt = 0; mt < 2; mt++) {
            half8_t af = *(const half8_t*)&xs[mt * 16 + row16][k0 + kgrp];
            acc[mt] = __builtin_amdgcn_mfma_f32_16x16x32_f16(af, bf, acc[mt], 0, 0, 0);
        }
    }

    const int colw = wave * 16 + row16;
    const float arc = arn[colw];
    const int rg = (lane >> 4) * 4;
    const int head = colw >> 3;
    const int nb = blockIdx.x * 32;
#pragma unroll
    for (int mt = 0; mt < 2; mt++) {
#pragma unroll
        for (int j = 0; j < 4; j++) {
            int n2 = nb + mt * 16 + rg + j;
            float val = acc[mt][j];
            hbuf_out[(size_t)n2 * HD + colw] = __float2half(val);
            float p = val * arc;
            p += __shfl_xor(p, 1);
            p += __shfl_xor(p, 2);
            p += __shfl_xor(p, 4);
            if ((lane & 7) == 0) er_out[(size_t)n2 * 8 + head] = p;
        }
    }
}

// ---------------- final agg (layer 2): f32 output ----------------
__global__ __launch_bounds__(256) void agg_kernel(
    const __half* __restrict__ hbuf, const float* __restrict__ al,
    const float* __restrict__ er, const int* __restrict__ deg,
    const int* __restrict__ csr_pad, const float* __restrict__ bias,
    float* __restrict__ out) {
    const int wave = threadIdx.x >> 6;
    const int lane = threadIdx.x & 63;
    const int oct = blockIdx.x * 4 + wave;
    const int g = lane >> 3;
    const int q = lane & 7;
    const int node = oct * 8 + g;
    const int cnt = min(deg[node], CAP);
    const float erv = er[(size_t)node * 8 + q];
    int4 rv = *(const int4*)&csr_pad[(size_t)node * CAP + q * 4];

    float4 av0 = *(const float4*)&al[q * 8];
    float4 av1 = *(const float4*)&al[q * 8 + 4];
    float4 bv0 = *(const float4*)&bias[q * 8];
    float4 bv1 = *(const float4*)&bias[q * 8 + 4];
    int cmax = cnt;
    cmax = max(cmax, __shfl_xor(cmax, 8));
    cmax = max(cmax, __shfl_xor(cmax, 16));
    cmax = max(cmax, __shfl_xor(cmax, 32));
    const int cm = max(cnt - 1, 0);
    const int gbase = lane & 56;

    int scl;
    {
        int bl = gbase + (cm >> 2);
        int c0 = __shfl(rv.x, bl), c1 = __shfl(rv.y, bl);
        int c2 = __shfl(rv.z, bl), c3 = __shfl(rv.w, bl);
        int cc = cm & 3;
        scl = cc == 0 ? c0 : (cc == 1 ? c1 : (cc == 2 ? c2 : c3));
        scl = (unsigned)scl < NN ? scl : 0;
    }

    float4 a0 = make_float4(0.f, 0.f, 0.f, 0.f);
    float4 a1 = make_float4(0.f, 0.f, 0.f, 0.f);
    float ssum = 0.f;

    for (int jj = 0; jj < cmax; jj += 8) {
        const int b0 = gbase + (jj >> 2);
        int sl[8];
        sl[0] = __shfl(rv.x, b0);     sl[1] = __shfl(rv.y, b0);
        sl[2] = __shfl(rv.z, b0);     sl[3] = __shfl(rv.w, b0);
        sl[4] = __shfl(rv.x, b0 + 1); sl[5] = __shfl(rv.y, b0 + 1);
        sl[6] = __shfl(rv.z, b0 + 1); sl[7] = __shfl(rv.w, b0 + 1);
        bool v[8];
#pragma unroll
        for (int t = 0; t < 8; t++) {
            v[t] = (jj + t) < cnt;
            int s = v[t] ? sl[t] : scl;
            sl[t] = (unsigned)s < NN ? s : 0;
        }
        uint4 hh[8];
#pragma unroll
        for (int t = 0; t < 8; t++) hh[t] = *(const uint4*)&hbuf[(size_t)sl[t] * HD + q * 8];
#pragma unroll
        for (int t = 0; t < 8; t++) {
            float2 u0 = __half22float2(*(__half2*)&hh[t].x);
            float2 u1 = __half22float2(*(__half2*)&hh[t].y);
            float2 u2 = __half22float2(*(__half2*)&hh[t].z);
            float2 u3 = __half22float2(*(__half2*)&hh[t].w);
            float elv = u0.x * av0.x + u0.y * av0.y + u1.x * av0.z + u1.y * av0.w
                      + u2.x * av1.x + u2.y * av1.y + u3.x * av1.z + u3.y * av1.w;
            float tt = elv + erv;
            tt = tt > 0.f ? tt : 0.2f * tt;
            float p = v[t] ? __expf(tt) : 0.f;
            ssum += p;
            a0.x = fmaf(p, u0.x, a0.x); a0.y = fmaf(p, u0.y, a0.y);
            a0.z = fmaf(p, u1.x, a0.z); a0.w = fmaf(p, u1.y, a0.w);
            a1.x = fmaf(p, u2.x, a1.x); a1.y = fmaf(p, u2.y, a1.y);
            a1.z = fmaf(p, u3.x, a1.z); a1.w = fmaf(p, u3.y, a1.w);
        }
    }

    float inv = ssum > 0.f ? 1.f / ssum : 0.f;
    float4 o0, o1;
    o0.x = fmaf(a0.x, inv, bv0.x); o0.y = fmaf(a0.y, inv, bv0.y);
    o0.z = fmaf(a0.z, inv, bv0.z); o0.w = fmaf(a0.w, inv, bv0.w);
    o1.x = fmaf(a1.x, inv, bv1.x); o1.y = fmaf(a1.y, inv, bv1.y);
    o1.z = fmaf(a1.z, inv, bv1.z); o1.w = fmaf(a1.w, inv, bv1.w);
    *(float4*)&out[(size_t)node * HD + q * 8] = o0;
    *(float4*)&out[(size_t)node * HD + q * 8 + 4] = o1;
}

// ---------------- launch ----------------

static inline size_t al512(size_t x) { return (x + 511) & ~(size_t)511; }

extern "C" void kernel_launch(void* const* d_in, const int* in_sizes, int n_in,
                              void* d_out, int out_size, void* d_ws, size_t ws_size,
                              hipStream_t stream) {
    const float* n_feat = (const float*)d_in[0];
    const int* src = (const int*)d_in[2];
    const int* dst = (const int*)d_in[3];
    const float* W[3]  = {(const float*)d_in[4], (const float*)d_in[8],  (const float*)d_in[12]};
    const float* al[3] = {(const float*)d_in[5], (const float*)d_in[9],  (const float*)d_in[13]};
    const float* ar[3] = {(const float*)d_in[6], (const float*)d_in[10], (const float*)d_in[14]};
    const float* bs[3] = {(const float*)d_in[7], (const float*)d_in[11], (const float*)d_in[15]};
    float* outF = (float*)d_out;

    char* ws = (char*)d_ws;
    size_t off = 0;
    int* deg     = (int*)(ws + off); off += (size_t)NN * 4;      // deg+cursor contiguous (zeroed together)
    int* cursor  = (int*)(ws + off); off += al512((size_t)NBUK * 4);
    int* csr_pad = (int*)(ws + off); off += al512((size_t)NN * CAP * 4);
    int2* bbuf   = (int2*)(ws + off); off += al512((size_t)NBUK * BCAP * 8);
    __half* hA   = (__half*)(ws + off); off += al512((size_t)NN * HD * 2);
    __half* hB   = (__half*)(ws + off); off += al512((size_t)NN * HD * 2);
    float* erA   = (float*)(ws + off); off += al512((size_t)NN * 8 * 4);
    float* erB   = (float*)(ws + off); off += al512((size_t)NN * 8 * 4);

    const int ZB = (NN + NBUK + 255) / 256;

    zero_kernel<<<ZB, 256, 0, stream>>>(deg, NN + NBUK);
    bucket_kernel<<<P1_BLOCKS, 256, 0, stream>>>(src, dst, cursor, bbuf);
    build_kernel<<<NBUK * P2_CHUNKS, 256, 0, stream>>>(cursor, bbuf, deg, csr_pad);

    lin_mfma<<<LINB, 256, 0, stream>>>(n_feat, W[0], ar[0], hA, erA);
    agg_lin_kernel<true><<<AGGB, 256, 0, stream>>>(hA, al[0], erA, deg, csr_pad, bs[0],
                                                   W[1], ar[1], hB, erB);
    agg_lin_kernel<true><<<AGGB, 256, 0, stream>>>(hB, al[1], erB, deg, csr_pad, bs[1],
                                                   W[2], ar[2], hA, erA);
    agg_kernel<<<AGGB, 256, 0, stream>>>(hA, al[2], erA, deg, csr_pad, bs[2], outF);
}

// Round 14
// 147.424 us; speedup vs baseline: 1.3493x; 1.0299x over previous
//
#include <hip/hip_runtime.h>
#include <hip/hip_fp16.h>
#include <math.h>

#define NN 100000
#define NE 800000
#define HH 8
#define DD 8
#define HD 64
#define CAP 32      // padded CSR row capacity; deg ~ Poisson(8), overflow negligible (validated R3-R13)

#define NBUK 200    // dst-range buckets (500 nodes each)
#define BNODES 500
#define BCAP 4400
#define P1_EPB 1024
#define P1_BLOCKS ((NE + P1_EPB - 1) / P1_EPB)   // 782
#define P2_CHUNKS 8
#define P2_CHUNK 550
#define BUILDB (NBUK * P2_CHUNKS)                // 1600

#define NOCT (NN / 8)        // 12500 octets, exact
#define AGGB (NOCT / 4)      // 3125 blocks x 4 waves (32 nodes/block)
#define LINB ((NN + 63) / 64)                    // 1563

typedef _Float16 half8_t __attribute__((ext_vector_type(8)));
typedef float f32x4_t __attribute__((ext_vector_type(4)));

// ---------------- pass1: bucket edges by dst range ----------------
__global__ __launch_bounds__(256) void bucket_kernel(const int* __restrict__ src,
                                                     const int* __restrict__ dst,
                                                     int* __restrict__ cursor,
                                                     int2* __restrict__ bbuf) {
    __shared__ int hist[NBUK];
    __shared__ int base[NBUK];
    const int tid = threadIdx.x;
    for (int i = tid; i < NBUK; i += 256) hist[i] = 0;
    __syncthreads();
    const int e0 = blockIdx.x * P1_EPB;
    int myb[4], myrank[4], mysrc[4], mydst[4];
#pragma unroll
    for (int i = 0; i < 4; i++) {
        int e = e0 + tid + i * 256;
        bool v = e < NE;
        int d = v ? dst[e] : 0;
        int b = d / BNODES;
        myb[i] = b;
        mydst[i] = d;
        mysrc[i] = v ? src[e] : 0;
        myrank[i] = v ? atomicAdd(&hist[b], 1) : -1;
    }
    __syncthreads();
    for (int i = tid; i < NBUK; i += 256) {
        int c = hist[i];
        base[i] = c > 0 ? atomicAdd(&cursor[i], c) : 0;
    }
    __syncthreads();
#pragma unroll
    for (int i = 0; i < 4; i++) {
        if (myrank[i] >= 0) {
            int pos = base[myb[i]] + myrank[i];
            if (pos < BCAP) bbuf[(size_t)myb[i] * BCAP + pos] = make_int2(mysrc[i], mydst[i]);
        }
    }
}

// ---------------- fused pass2 (CSR scatter) + lin0 (MFMA GEMM) ----------------
// Blocks 0..BUILDB-1: per-bucket scatter into padded CSR (disjoint data from
// lin0). Blocks BUILDB..BUILDB+LINB-1: h=x@W0 (K=128, f32 input) + er.
// Both products are consumed only by agg_lin0 -> legal to co-schedule; saves
// one dispatch boundary and overlaps lin0 under build's atomic latency.
// Note: LDS (34.8KB, from the lin branch) is allocated for build blocks too
// -> build capped at 4 blocks/CU; acceptable (1600 short blocks, 256 CUs).
__global__ __launch_bounds__(256) void build_lin_kernel(
    const int* __restrict__ cursor, const int2* __restrict__ bbuf,
    int* __restrict__ deg, int* __restrict__ csr_pad,
    const float* __restrict__ x, const float* __restrict__ W,
    const float* __restrict__ ar, __half* __restrict__ h, float* __restrict__ er) {
    constexpr int K = 128, KP = K + 8;
    __shared__ _Float16 xh[64][KP];
    __shared__ _Float16 wt[64][KP];
    const int tid = threadIdx.x;

    if (blockIdx.x < BUILDB) {
        const int b = blockIdx.x % NBUK;
        const int chunk = blockIdx.x / NBUK;
        const int cnt = min(cursor[b], BCAP);
        const int hi = min(chunk * P2_CHUNK + P2_CHUNK, cnt);
        const int2* bb = bbuf + (size_t)b * BCAP;
        for (int i = chunk * P2_CHUNK + tid; i < hi; i += 256) {
            int2 p = bb[i];
            int pos = atomicAdd(&deg[p.y], 1);
            if (pos < CAP) csr_pad[(size_t)p.y * CAP + pos] = p.x;
        }
        return;
    }

    const int w = tid >> 6;
    const int l = tid & 63;
    const int nb = (blockIdx.x - BUILDB) * 64;

#pragma unroll
    for (int it = 0; it < 8; it++) {
        int idx = tid + it * 256;
        int r = idx / (K / 4);
        int c4 = idx % (K / 4);
        int node = nb + r; if (node >= NN) node = NN - 1;
        float4 v = *(const float4*)&x[(size_t)node * K + c4 * 4];
        union { _Float16 f[4]; uint2 u; } pk;
        pk.f[0] = (_Float16)v.x; pk.f[1] = (_Float16)v.y;
        pk.f[2] = (_Float16)v.z; pk.f[3] = (_Float16)v.w;
        *(uint2*)&xh[r][c4 * 4] = pk.u;
    }
#pragma unroll
    for (int it = 0; it < 8; it++) {
        int idx = tid + it * 256;
        int k = idx >> 4;
        int c0 = (idx & 15) * 4;
        float4 v = *(const float4*)&W[(size_t)k * 64 + c0];
        wt[c0][k]     = (_Float16)v.x;
        wt[c0 + 1][k] = (_Float16)v.y;
        wt[c0 + 2][k] = (_Float16)v.z;
        wt[c0 + 3][k] = (_Float16)v.w;
    }
    __syncthreads();

    const int row16 = l & 15;
    const int kgrp = (l >> 4) * 8;
    f32x4_t acc[4];
#pragma unroll
    for (int r = 0; r < 4; r++) acc[r] = (f32x4_t){0.f, 0.f, 0.f, 0.f};

#pragma unroll
    for (int k0 = 0; k0 < K; k0 += 32) {
        half8_t bf = *(const half8_t*)&wt[w * 16 + row16][k0 + kgrp];
#pragma unroll
        for (int r = 0; r < 4; r++) {
            half8_t af = *(const half8_t*)&xh[r * 16 + row16][k0 + kgrp];
            acc[r] = __builtin_amdgcn_mfma_f32_16x16x32_f16(af, bf, acc[r], 0, 0, 0);
        }
    }

    const int colw = w * 16 + row16;
    const float arc = ar[colw];
    const int rg = (l >> 4) * 4;
    const int head = colw >> 3;
#pragma unroll
    for (int r = 0; r < 4; r++) {
#pragma unroll
        for (int j = 0; j < 4; j++) {
            int node = nb + r * 16 + rg + j;
            float val = acc[r][j];
            if (node < NN) h[(size_t)node * HD + colw] = __float2half(val);
            float p = val * arc;
            p += __shfl_xor(p, 1);
            p += __shfl_xor(p, 2);
            p += __shfl_xor(p, 4);
            if ((l & 7) == 0 && node < NN) er[(size_t)node * 8 + head] = p;
        }
    }
}

// ---------------- fused agg + next-layer lin (unchanged from R13) ----------------
template <bool ACT>
__global__ __launch_bounds__(256) void agg_lin_kernel(
    const __half* __restrict__ hbuf_in, const float* __restrict__ al,
    const float* __restrict__ er_in, const int* __restrict__ deg,
    const int* __restrict__ csr_pad, const float* __restrict__ bias,
    const float* __restrict__ Wn, const float* __restrict__ arn,
    __half* __restrict__ hbuf_out, float* __restrict__ er_out) {
    __shared__ _Float16 wt[64][72];   // W_next transposed, fp16
    __shared__ _Float16 xs[32][72];   // this block's 32 output rows, fp16
    const int tid = threadIdx.x;
    const int wave = tid >> 6;
    const int lane = tid & 63;
    const int oct = blockIdx.x * 4 + wave;
    const int g = lane >> 3;
    const int q = lane & 7;
    const int node = oct * 8 + g;

#pragma unroll
    for (int it = 0; it < 4; it++) {
        int idx = tid + it * 256;
        int k = idx >> 4;
        int c0 = (idx & 15) * 4;
        float4 v = *(const float4*)&Wn[(size_t)k * 64 + c0];
        wt[c0][k]     = (_Float16)v.x;
        wt[c0 + 1][k] = (_Float16)v.y;
        wt[c0 + 2][k] = (_Float16)v.z;
        wt[c0 + 3][k] = (_Float16)v.w;
    }

    const int cnt = min(deg[node], CAP);
    const float erv = er_in[(size_t)node * 8 + q];
    int4 rv = *(const int4*)&csr_pad[(size_t)node * CAP + q * 4];

    float4 av0 = *(const float4*)&al[q * 8];
    float4 av1 = *(const float4*)&al[q * 8 + 4];
    float4 bv0 = *(const float4*)&bias[q * 8];
    float4 bv1 = *(const float4*)&bias[q * 8 + 4];
    int cmax = cnt;
    cmax = max(cmax, __shfl_xor(cmax, 8));
    cmax = max(cmax, __shfl_xor(cmax, 16));
    cmax = max(cmax, __shfl_xor(cmax, 32));
    const int cm = max(cnt - 1, 0);
    const int gbase = lane & 56;

    int scl;
    {
        int bl = gbase + (cm >> 2);
        int c0 = __shfl(rv.x, bl), c1 = __shfl(rv.y, bl);
        int c2 = __shfl(rv.z, bl), c3 = __shfl(rv.w, bl);
        int cc = cm & 3;
        scl = cc == 0 ? c0 : (cc == 1 ? c1 : (cc == 2 ? c2 : c3));
        scl = (unsigned)scl < NN ? scl : 0;
    }

    float4 a0 = make_float4(0.f, 0.f, 0.f, 0.f);
    float4 a1 = make_float4(0.f, 0.f, 0.f, 0.f);
    float ssum = 0.f;

    for (int jj = 0; jj < cmax; jj += 8) {
        const int b0 = gbase + (jj >> 2);
        int sl[8];
        sl[0] = __shfl(rv.x, b0);     sl[1] = __shfl(rv.y, b0);
        sl[2] = __shfl(rv.z, b0);     sl[3] = __shfl(rv.w, b0);
        sl[4] = __shfl(rv.x, b0 + 1); sl[5] = __shfl(rv.y, b0 + 1);
        sl[6] = __shfl(rv.z, b0 + 1); sl[7] = __shfl(rv.w, b0 + 1);
        bool v[8];
#pragma unroll
        for (int t = 0; t < 8; t++) {
            v[t] = (jj + t) < cnt;
            int s = v[t] ? sl[t] : scl;
            sl[t] = (unsigned)s < NN ? s : 0;
        }
        uint4 hh[8];
#pragma unroll
        for (int t = 0; t < 8; t++) hh[t] = *(const uint4*)&hbuf_in[(size_t)sl[t] * HD + q * 8];
#pragma unroll
        for (int t = 0; t < 8; t++) {
            float2 u0 = __half22float2(*(__half2*)&hh[t].x);
            float2 u1 = __half22float2(*(__half2*)&hh[t].y);
            float2 u2 = __half22float2(*(__half2*)&hh[t].z);
            float2 u3 = __half22float2(*(__half2*)&hh[t].w);
            float elv = u0.x * av0.x + u0.y * av0.y + u1.x * av0.z + u1.y * av0.w
                      + u2.x * av1.x + u2.y * av1.y + u3.x * av1.z + u3.y * av1.w;
            float tt = elv + erv;
            tt = tt > 0.f ? tt : 0.2f * tt;
            float p = v[t] ? __expf(tt) : 0.f;
            ssum += p;
            a0.x = fmaf(p, u0.x, a0.x); a0.y = fmaf(p, u0.y, a0.y);
            a0.z = fmaf(p, u1.x, a0.z); a0.w = fmaf(p, u1.y, a0.w);
            a1.x = fmaf(p, u2.x, a1.x); a1.y = fmaf(p, u2.y, a1.y);
            a1.z = fmaf(p, u3.x, a1.z); a1.w = fmaf(p, u3.y, a1.w);
        }
    }

    float inv = ssum > 0.f ? 1.f / ssum : 0.f;
    float o0x = fmaf(a0.x, inv, bv0.x), o0y = fmaf(a0.y, inv, bv0.y);
    float o0z = fmaf(a0.z, inv, bv0.z), o0w = fmaf(a0.w, inv, bv0.w);
    float o1x = fmaf(a1.x, inv, bv1.x), o1y = fmaf(a1.y, inv, bv1.y);
    float o1z = fmaf(a1.z, inv, bv1.z), o1w = fmaf(a1.w, inv, bv1.w);
    if (ACT) {
        o0x = o0x > 0.f ? o0x : 0.01f * o0x;
        o0y = o0y > 0.f ? o0y : 0.01f * o0y;
        o0z = o0z > 0.f ? o0z : 0.01f * o0z;
        o0w = o0w > 0.f ? o0w : 0.01f * o0w;
        o1x = o1x > 0.f ? o1x : 0.01f * o1x;
        o1y = o1y > 0.f ? o1y : 0.01f * o1y;
        o1z = o1z > 0.f ? o1z : 0.01f * o1z;
        o1w = o1w > 0.f ? o1w : 0.01f * o1w;
    }
    {
        union { _Float16 f[8]; uint4 u; } pk;
        pk.f[0] = (_Float16)o0x; pk.f[1] = (_Float16)o0y;
        pk.f[2] = (_Float16)o0z; pk.f[3] = (_Float16)o0w;
        pk.f[4] = (_Float16)o1x; pk.f[5] = (_Float16)o1y;
        pk.f[6] = (_Float16)o1z; pk.f[7] = (_Float16)o1w;
        *(uint4*)&xs[wave * 8 + g][q * 8] = pk.u;
    }
    __syncthreads();

    const int row16 = lane & 15;
    const int kgrp = (lane >> 4) * 8;
    f32x4_t acc[2];
    acc[0] = (f32x4_t){0.f, 0.f, 0.f, 0.f};
    acc[1] = (f32x4_t){0.f, 0.f, 0.f, 0.f};
#pragma unroll
    for (int k0 = 0; k0 < 64; k0 += 32) {
        half8_t bf = *(const half8_t*)&wt[wave * 16 + row16][k0 + kgrp];
#pragma unroll
        for (int mt = 0; mt < 2; mt++) {
            half8_t af = *(const half8_t*)&xs[mt * 16 + row16][k0 + kgrp];
            acc[mt] = __builtin_amdgcn_mfma_f32_16x16x32_f16(af, bf, acc[mt], 0, 0, 0);
        }
    }

    const int colw = wave * 16 + row16;
    const float arc = arn[colw];
    const int rg = (lane >> 4) * 4;
    const int head = colw >> 3;
    const int nb = blockIdx.x * 32;
#pragma unroll
    for (int mt = 0; mt < 2; mt++) {
#pragma unroll
        for (int j = 0; j < 4; j++) {
            int n2 = nb + mt * 16 + rg + j;
            float val = acc[mt][j];
            hbuf_out[(size_t)n2 * HD + colw] = __float2half(val);
            float p = val * arc;
            p += __shfl_xor(p, 1);
            p += __shfl_xor(p, 2);
            p += __shfl_xor(p, 4);
            if ((lane & 7) == 0) er_out[(size_t)n2 * 8 + head] = p;
        }
    }
}

// ---------------- final agg (layer 2): f32 output (unchanged from R13) ----------------
__global__ __launch_bounds__(256) void agg_kernel(
    const __half* __restrict__ hbuf, const float* __restrict__ al,
    const float* __restrict__ er, const int* __restrict__ deg,
    const int* __restrict__ csr_pad, const float* __restrict__ bias,
    float* __restrict__ out) {
    const int wave = threadIdx.x >> 6;
    const int lane = threadIdx.x & 63;
    const int oct = blockIdx.x * 4 + wave;
    const int g = lane >> 3;
    const int q = lane & 7;
    const int node = oct * 8 + g;
    const int cnt = min(deg[node], CAP);
    const float erv = er[(size_t)node * 8 + q];
    int4 rv = *(const int4*)&csr_pad[(size_t)node * CAP + q * 4];

    float4 av0 = *(const float4*)&al[q * 8];
    float4 av1 = *(const float4*)&al[q * 8 + 4];
    float4 bv0 = *(const float4*)&bias[q * 8];
    float4 bv1 = *(const float4*)&bias[q * 8 + 4];
    int cmax = cnt;
    cmax = max(cmax, __shfl_xor(cmax, 8));
    cmax = max(cmax, __shfl_xor(cmax, 16));
    cmax = max(cmax, __shfl_xor(cmax, 32));
    const int cm = max(cnt - 1, 0);
    const int gbase = lane & 56;

    int scl;
    {
        int bl = gbase + (cm >> 2);
        int c0 = __shfl(rv.x, bl), c1 = __shfl(rv.y, bl);
        int c2 = __shfl(rv.z, bl), c3 = __shfl(rv.w, bl);
        int cc = cm & 3;
        scl = cc == 0 ? c0 : (cc == 1 ? c1 : (cc == 2 ? c2 : c3));
        scl = (unsigned)scl < NN ? scl : 0;
    }

    float4 a0 = make_float4(0.f, 0.f, 0.f, 0.f);
    float4 a1 = make_float4(0.f, 0.f, 0.f, 0.f);
    float ssum = 0.f;

    for (int jj = 0; jj < cmax; jj += 8) {
        const int b0 = gbase + (jj >> 2);
        int sl[8];
        sl[0] = __shfl(rv.x, b0);     sl[1] = __shfl(rv.y, b0);
        sl[2] = __shfl(rv.z, b0);     sl[3] = __shfl(rv.w, b0);
        sl[4] = __shfl(rv.x, b0 + 1); sl[5] = __shfl(rv.y, b0 + 1);
        sl[6] = __shfl(rv.z, b0 + 1); sl[7] = __shfl(rv.w, b0 + 1);
        bool v[8];
#pragma unroll
        for (int t = 0; t < 8; t++) {
            v[t] = (jj + t) < cnt;
            int s = v[t] ? sl[t] : scl;
            sl[t] = (unsigned)s < NN ? s : 0;
        }
        uint4 hh[8];
#pragma unroll
        for (int t = 0; t < 8; t++) hh[t] = *(const uint4*)&hbuf[(size_t)sl[t] * HD + q * 8];
#pragma unroll
        for (int t = 0; t < 8; t++) {
            float2 u0 = __half22float2(*(__half2*)&hh[t].x);
            float2 u1 = __half22float2(*(__half2*)&hh[t].y);
            float2 u2 = __half22float2(*(__half2*)&hh[t].z);
            float2 u3 = __half22float2(*(__half2*)&hh[t].w);
            float elv = u0.x * av0.x + u0.y * av0.y + u1.x * av0.z + u1.y * av0.w
                      + u2.x * av1.x + u2.y * av1.y + u3.x * av1.z + u3.y * av1.w;
            float tt = elv + erv;
            tt = tt > 0.f ? tt : 0.2f * tt;
            float p = v[t] ? __expf(tt) : 0.f;
            ssum += p;
            a0.x = fmaf(p, u0.x, a0.x); a0.y = fmaf(p, u0.y, a0.y);
            a0.z = fmaf(p, u1.x, a0.z); a0.w = fmaf(p, u1.y, a0.w);
            a1.x = fmaf(p, u2.x, a1.x); a1.y = fmaf(p, u2.y, a1.y);
            a1.z = fmaf(p, u3.x, a1.z); a1.w = fmaf(p, u3.y, a1.w);
        }
    }

    float inv = ssum > 0.f ? 1.f / ssum : 0.f;
    float4 o0, o1;
    o0.x = fmaf(a0.x, inv, bv0.x); o0.y = fmaf(a0.y, inv, bv0.y);
    o0.z = fmaf(a0.z, inv, bv0.z); o0.w = fmaf(a0.w, inv, bv0.w);
    o1.x = fmaf(a1.x, inv, bv1.x); o1.y = fmaf(a1.y, inv, bv1.y);
    o1.z = fmaf(a1.z, inv, bv1.z); o1.w = fmaf(a1.w, inv, bv1.w);
    *(float4*)&out[(size_t)node * HD + q * 8] = o0;
    *(float4*)&out[(size_t)node * HD + q * 8 + 4] = o1;
}

// ---------------- launch ----------------

static inline size_t al512(size_t x) { return (x + 511) & ~(size_t)511; }

extern "C" void kernel_launch(void* const* d_in, const int* in_sizes, int n_in,
                              void* d_out, int out_size, void* d_ws, size_t ws_size,
                              hipStream_t stream) {
    const float* n_feat = (const float*)d_in[0];
    const int* src = (const int*)d_in[2];
    const int* dst = (const int*)d_in[3];
    const float* W[3]  = {(const float*)d_in[4], (const float*)d_in[8],  (const float*)d_in[12]};
    const float* al[3] = {(const float*)d_in[5], (const float*)d_in[9],  (const float*)d_in[13]};
    const float* ar[3] = {(const float*)d_in[6], (const float*)d_in[10], (const float*)d_in[14]};
    const float* bs[3] = {(const float*)d_in[7], (const float*)d_in[11], (const float*)d_in[15]};
    float* outF = (float*)d_out;

    char* ws = (char*)d_ws;
    size_t off = 0;
    int* deg     = (int*)(ws + off); off += (size_t)NN * 4;      // deg+cursor contiguous (one memset)
    int* cursor  = (int*)(ws + off); off += al512((size_t)NBUK * 4);
    int* csr_pad = (int*)(ws + off); off += al512((size_t)NN * CAP * 4);
    int2* bbuf   = (int2*)(ws + off); off += al512((size_t)NBUK * BCAP * 8);
    __half* hA   = (__half*)(ws + off); off += al512((size_t)NN * HD * 2);
    __half* hB   = (__half*)(ws + off); off += al512((size_t)NN * HD * 2);
    float* erA   = (float*)(ws + off); off += al512((size_t)NN * 8 * 4);
    float* erB   = (float*)(ws + off); off += al512((size_t)NN * 8 * 4);

    // deg + cursor zeroed in one async fill (capture-safe)
    hipMemsetAsync(deg, 0, (size_t)(NN + NBUK) * 4, stream);
    bucket_kernel<<<P1_BLOCKS, 256, 0, stream>>>(src, dst, cursor, bbuf);
    build_lin_kernel<<<BUILDB + LINB, 256, 0, stream>>>(cursor, bbuf, deg, csr_pad,
                                                        n_feat, W[0], ar[0], hA, erA);
    agg_lin_kernel<true><<<AGGB, 256, 0, stream>>>(hA, al[0], erA, deg, csr_pad, bs[0],
                                                   W[1], ar[1], hB, erB);
    agg_lin_kernel<true><<<AGGB, 256, 0, stream>>>(hB, al[1], erB, deg, csr_pad, bs[1],
                                                   W[2], ar[2], hA, erA);
    agg_kernel<<<AGGB, 256, 0, stream>>>(hA, al[2], erA, deg, csr_pad, bs[2], outF);
}

// Round 15
// 136.330 us; speedup vs baseline: 1.4591x; 1.0814x over previous
//
#include <hip/hip_runtime.h>
#include <hip/hip_fp16.h>
#include <math.h>

#define NN 100000
#define NE 800000
#define HH 8
#define DD 8
#define HD 64
#define CAP 32      // padded CSR row capacity; deg ~ Poisson(8), overflow negligible (validated R3-R14)

#define NBUK 200    // dst-range buckets (500 nodes each; NN = NBUK*BNODES exactly)
#define BNODES 500
#define BCAP 4400
#define P1_EPB 1024
#define P1_BLOCKS ((NE + P1_EPB - 1) / P1_EPB)   // 782

#define NOCT (NN / 8)        // 12500 octets, exact
#define AGGB (NOCT / 4)      // 3125 blocks x 4 waves (32 nodes/block)
#define LINB ((NN + 63) / 64)                    // 1563

typedef _Float16 half8_t __attribute__((ext_vector_type(8)));
typedef float f32x4_t __attribute__((ext_vector_type(4)));

// ---------------- pass1: bucket edges by dst range (unchanged) ----------------
__global__ __launch_bounds__(256) void bucket_kernel(const int* __restrict__ src,
                                                     const int* __restrict__ dst,
                                                     int* __restrict__ cursor,
                                                     int2* __restrict__ bbuf) {
    __shared__ int hist[NBUK];
    __shared__ int base[NBUK];
    const int tid = threadIdx.x;
    for (int i = tid; i < NBUK; i += 256) hist[i] = 0;
    __syncthreads();
    const int e0 = blockIdx.x * P1_EPB;
    int myb[4], myrank[4], mysrc[4], mydst[4];
#pragma unroll
    for (int i = 0; i < 4; i++) {
        int e = e0 + tid + i * 256;
        bool v = e < NE;
        int d = v ? dst[e] : 0;
        int b = d / BNODES;
        myb[i] = b;
        mydst[i] = d;
        mysrc[i] = v ? src[e] : 0;
        myrank[i] = v ? atomicAdd(&hist[b], 1) : -1;
    }
    __syncthreads();
    for (int i = tid; i < NBUK; i += 256) {
        int c = hist[i];
        base[i] = c > 0 ? atomicAdd(&cursor[i], c) : 0;
    }
    __syncthreads();
#pragma unroll
    for (int i = 0; i < 4; i++) {
        if (myrank[i] >= 0) {
            int pos = base[myb[i]] + myrank[i];
            if (pos < BCAP) bbuf[(size_t)myb[i] * BCAP + pos] = make_int2(mysrc[i], mydst[i]);
        }
    }
}

// ---------------- pass2: per-bucket COUNTING SORT -> deg + padded CSR ----------------
// R15: replaces the global-atomic scatter (R14's 43us build_lin). One block
// per bucket (512 thr): LDS hist[500] -> wave scan -> LDS-cursor scatter.
// ZERO global atomics; deg written coalesced; csr writes confined to the
// bucket's 64KB window (L2-resident).
__global__ __launch_bounds__(512) void build2_kernel(const int* __restrict__ cursor,
                                                     const int2* __restrict__ bbuf,
                                                     int* __restrict__ deg,
                                                     int* __restrict__ csr_pad) {
    __shared__ int hist[512];
    __shared__ int base[512];
    __shared__ int cur[512];
    __shared__ int wsum[8];
    const int tid = threadIdx.x;
    const int wid = tid >> 6;
    const int lane = tid & 63;
    const int b = blockIdx.x;
    const int node0 = b * BNODES;
    const int cnt = min(cursor[b], BCAP);
    const int2* bb = bbuf + (size_t)b * BCAP;

    hist[tid] = 0;
    __syncthreads();
    for (int i = tid; i < cnt; i += 512) {
        int d = bb[i].y - node0;
        atomicAdd(&hist[d], 1);
    }
    __syncthreads();
    int v = hist[tid];
    if (tid < BNODES) deg[node0 + tid] = v;     // coalesced, non-atomic
    // block-wide exclusive scan of 512 bins
    int inc = v;
    for (int off = 1; off < 64; off <<= 1) {
        int t = __shfl_up(inc, off);
        if (lane >= off) inc += t;
    }
    if (lane == 63) wsum[wid] = inc;
    __syncthreads();
    if (wid == 0) {
        int s = (lane < 8) ? wsum[lane] : 0;
        int si = s;
        for (int off = 1; off < 8; off <<= 1) {
            int t = __shfl_up(si, off);
            if (lane >= off) si += t;
        }
        if (lane < 8) wsum[lane] = si - s;      // exclusive wave offset
    }
    __syncthreads();
    int excl = inc - v + wsum[wid];
    base[tid] = excl;
    cur[tid] = excl;
    __syncthreads();
    for (int i = tid; i < cnt; i += 512) {
        int2 p = bb[i];
        int d = p.y - node0;
        int pos = atomicAdd(&cur[d], 1);        // LDS atomic
        int slot = pos - base[d];
        if (slot < CAP) csr_pad[(size_t)p.y * CAP + slot] = p.x;
    }
}

// ---------------- lin0: MFMA fp16 GEMM (K=128, f32 input) ----------------
// R15: wt staging re-mapped -- lane owns (col c, 4 consecutive k): global
// reads stay coalesced per k-row; LDS write banks step 4/lane (was 8-way
// same-bank -> 3.3M conflicts in R14).
__global__ __launch_bounds__(256) void lin_mfma(
    const float* __restrict__ x, const float* __restrict__ W,
    const float* __restrict__ ar,
    __half* __restrict__ h, float* __restrict__ er) {
    constexpr int K = 128, KP = K + 8;
    __shared__ _Float16 xh[64][KP];
    __shared__ _Float16 wt[64][KP];
    const int tid = threadIdx.x;
    const int w = tid >> 6;
    const int l = tid & 63;
    const int nb = blockIdx.x * 64;

#pragma unroll
    for (int it = 0; it < 8; it++) {
        int idx = tid + it * 256;
        int r = idx / (K / 4);
        int c4 = idx % (K / 4);
        int node = nb + r; if (node >= NN) node = NN - 1;
        float4 v = *(const float4*)&x[(size_t)node * K + c4 * 4];
        union { _Float16 f[4]; uint2 u; } pk;
        pk.f[0] = (_Float16)v.x; pk.f[1] = (_Float16)v.y;
        pk.f[2] = (_Float16)v.z; pk.f[3] = (_Float16)v.w;
        *(uint2*)&xh[r][c4 * 4] = pk.u;
    }
    // W^T staging: idx -> (c = idx&63, k4 = idx>>6); 64*32 = 2048 = 8*256
#pragma unroll
    for (int it = 0; it < 8; it++) {
        int idx = tid + it * 256;
        int c = idx & 63;
        int k4 = idx >> 6;
        union { _Float16 f[4]; uint2 u; } pk;
        pk.f[0] = (_Float16)W[(size_t)(k4 * 4 + 0) * 64 + c];
        pk.f[1] = (_Float16)W[(size_t)(k4 * 4 + 1) * 64 + c];
        pk.f[2] = (_Float16)W[(size_t)(k4 * 4 + 2) * 64 + c];
        pk.f[3] = (_Float16)W[(size_t)(k4 * 4 + 3) * 64 + c];
        *(uint2*)&wt[c][k4 * 4] = pk.u;
    }
    __syncthreads();

    const int row16 = l & 15;
    const int kgrp = (l >> 4) * 8;
    f32x4_t acc[4];
#pragma unroll
    for (int r = 0; r < 4; r++) acc[r] = (f32x4_t){0.f, 0.f, 0.f, 0.f};

#pragma unroll
    for (int k0 = 0; k0 < K; k0 += 32) {
        half8_t bf = *(const half8_t*)&wt[w * 16 + row16][k0 + kgrp];
#pragma unroll
        for (int r = 0; r < 4; r++) {
            half8_t af = *(const half8_t*)&xh[r * 16 + row16][k0 + kgrp];
            acc[r] = __builtin_amdgcn_mfma_f32_16x16x32_f16(af, bf, acc[r], 0, 0, 0);
        }
    }

    const int colw = w * 16 + row16;
    const float arc = ar[colw];
    const int rg = (l >> 4) * 4;
    const int head = colw >> 3;
#pragma unroll
    for (int r = 0; r < 4; r++) {
#pragma unroll
        for (int j = 0; j < 4; j++) {
            int node = nb + r * 16 + rg + j;
            float val = acc[r][j];
            if (node < NN) h[(size_t)node * HD + colw] = __float2half(val);
            float p = val * arc;
            p += __shfl_xor(p, 1);
            p += __shfl_xor(p, 2);
            p += __shfl_xor(p, 4);
            if ((l & 7) == 0 && node < NN) er[(size_t)node * 8 + head] = p;
        }
    }
}

// ---------------- fused agg + next-layer lin ----------------
// R15: wt staging conflict-fixed (same remap); xs padded [32][88] (2-way max
// on write and MFMA read, rows 16B-aligned: 88*2=176=11*16).
template <bool ACT>
__global__ __launch_bounds__(256) void agg_lin_kernel(
    const __half* __restrict__ hbuf_in, const float* __restrict__ al,
    const float* __restrict__ er_in, const int* __restrict__ deg,
    const int* __restrict__ csr_pad, const float* __restrict__ bias,
    const float* __restrict__ Wn, const float* __restrict__ arn,
    __half* __restrict__ hbuf_out, float* __restrict__ er_out) {
    __shared__ _Float16 wt[64][72];   // W_next transposed, fp16
    __shared__ _Float16 xs[32][88];   // this block's 32 output rows, fp16
    const int tid = threadIdx.x;
    const int wave = tid >> 6;
    const int lane = tid & 63;
    const int oct = blockIdx.x * 4 + wave;
    const int g = lane >> 3;
    const int q = lane & 7;
    const int node = oct * 8 + g;

    // W^T staging: idx -> (c = idx&63, k4 = idx>>6); 64*16 = 1024 = 4*256
#pragma unroll
    for (int it = 0; it < 4; it++) {
        int idx = tid + it * 256;
        int c = idx & 63;
        int k4 = idx >> 6;
        union { _Float16 f[4]; uint2 u; } pk;
        pk.f[0] = (_Float16)Wn[(size_t)(k4 * 4 + 0) * 64 + c];
        pk.f[1] = (_Float16)Wn[(size_t)(k4 * 4 + 1) * 64 + c];
        pk.f[2] = (_Float16)Wn[(size_t)(k4 * 4 + 2) * 64 + c];
        pk.f[3] = (_Float16)Wn[(size_t)(k4 * 4 + 3) * 64 + c];
        *(uint2*)&wt[c][k4 * 4] = pk.u;
    }

    const int cnt = min(deg[node], CAP);
    const float erv = er_in[(size_t)node * 8 + q];
    int4 rv = *(const int4*)&csr_pad[(size_t)node * CAP + q * 4];

    float4 av0 = *(const float4*)&al[q * 8];
    float4 av1 = *(const float4*)&al[q * 8 + 4];
    float4 bv0 = *(const float4*)&bias[q * 8];
    float4 bv1 = *(const float4*)&bias[q * 8 + 4];
    int cmax = cnt;
    cmax = max(cmax, __shfl_xor(cmax, 8));
    cmax = max(cmax, __shfl_xor(cmax, 16));
    cmax = max(cmax, __shfl_xor(cmax, 32));
    const int cm = max(cnt - 1, 0);
    const int gbase = lane & 56;

    int scl;
    {
        int bl = gbase + (cm >> 2);
        int c0 = __shfl(rv.x, bl), c1 = __shfl(rv.y, bl);
        int c2 = __shfl(rv.z, bl), c3 = __shfl(rv.w, bl);
        int cc = cm & 3;
        scl = cc == 0 ? c0 : (cc == 1 ? c1 : (cc == 2 ? c2 : c3));
        scl = (unsigned)scl < NN ? scl : 0;
    }

    float4 a0 = make_float4(0.f, 0.f, 0.f, 0.f);
    float4 a1 = make_float4(0.f, 0.f, 0.f, 0.f);
    float ssum = 0.f;

    for (int jj = 0; jj < cmax; jj += 8) {
        const int b0 = gbase + (jj >> 2);
        int sl[8];
        sl[0] = __shfl(rv.x, b0);     sl[1] = __shfl(rv.y, b0);
        sl[2] = __shfl(rv.z, b0);     sl[3] = __shfl(rv.w, b0);
        sl[4] = __shfl(rv.x, b0 + 1); sl[5] = __shfl(rv.y, b0 + 1);
        sl[6] = __shfl(rv.z, b0 + 1); sl[7] = __shfl(rv.w, b0 + 1);
        bool v[8];
#pragma unroll
        for (int t = 0; t < 8; t++) {
            v[t] = (jj + t) < cnt;
            int s = v[t] ? sl[t] : scl;
            sl[t] = (unsigned)s < NN ? s : 0;
        }
        uint4 hh[8];
#pragma unroll
        for (int t = 0; t < 8; t++) hh[t] = *(const uint4*)&hbuf_in[(size_t)sl[t] * HD + q * 8];
#pragma unroll
        for (int t = 0; t < 8; t++) {
            float2 u0 = __half22float2(*(__half2*)&hh[t].x);
            float2 u1 = __half22float2(*(__half2*)&hh[t].y);
            float2 u2 = __half22float2(*(__half2*)&hh[t].z);
            float2 u3 = __half22float2(*(__half2*)&hh[t].w);
            float elv = u0.x * av0.x + u0.y * av0.y + u1.x * av0.z + u1.y * av0.w
                      + u2.x * av1.x + u2.y * av1.y + u3.x * av1.z + u3.y * av1.w;
            float tt = elv + erv;
            tt = tt > 0.f ? tt : 0.2f * tt;
            float p = v[t] ? __expf(tt) : 0.f;
            ssum += p;
            a0.x = fmaf(p, u0.x, a0.x); a0.y = fmaf(p, u0.y, a0.y);
            a0.z = fmaf(p, u1.x, a0.z); a0.w = fmaf(p, u1.y, a0.w);
            a1.x = fmaf(p, u2.x, a1.x); a1.y = fmaf(p, u2.y, a1.y);
            a1.z = fmaf(p, u3.x, a1.z); a1.w = fmaf(p, u3.y, a1.w);
        }
    }

    float inv = ssum > 0.f ? 1.f / ssum : 0.f;
    float o0x = fmaf(a0.x, inv, bv0.x), o0y = fmaf(a0.y, inv, bv0.y);
    float o0z = fmaf(a0.z, inv, bv0.z), o0w = fmaf(a0.w, inv, bv0.w);
    float o1x = fmaf(a1.x, inv, bv1.x), o1y = fmaf(a1.y, inv, bv1.y);
    float o1z = fmaf(a1.z, inv, bv1.z), o1w = fmaf(a1.w, inv, bv1.w);
    if (ACT) {
        o0x = o0x > 0.f ? o0x : 0.01f * o0x;
        o0y = o0y > 0.f ? o0y : 0.01f * o0y;
        o0z = o0z > 0.f ? o0z : 0.01f * o0z;
        o0w = o0w > 0.f ? o0w : 0.01f * o0w;
        o1x = o1x > 0.f ? o1x : 0.01f * o1x;
        o1y = o1y > 0.f ? o1y : 0.01f * o1y;
        o1z = o1z > 0.f ? o1z : 0.01f * o1z;
        o1w = o1w > 0.f ? o1w : 0.01f * o1w;
    }
    {
        union { _Float16 f[8]; uint4 u; } pk;
        pk.f[0] = (_Float16)o0x; pk.f[1] = (_Float16)o0y;
        pk.f[2] = (_Float16)o0z; pk.f[3] = (_Float16)o0w;
        pk.f[4] = (_Float16)o1x; pk.f[5] = (_Float16)o1y;
        pk.f[6] = (_Float16)o1z; pk.f[7] = (_Float16)o1w;
        *(uint4*)&xs[wave * 8 + g][q * 8] = pk.u;
    }
    __syncthreads();

    const int row16 = lane & 15;
    const int kgrp = (lane >> 4) * 8;
    f32x4_t acc[2];
    acc[0] = (f32x4_t){0.f, 0.f, 0.f, 0.f};
    acc[1] = (f32x4_t){0.f, 0.f, 0.f, 0.f};
#pragma unroll
    for (int k0 = 0; k0 < 64; k0 += 32) {
        half8_t bf = *(const half8_t*)&wt[wave * 16 + row16][k0 + kgrp];
#pragma unroll
        for (int mt = 0; mt < 2; mt++) {
            half8_t af = *(const half8_t*)&xs[mt * 16 + row16][k0 + kgrp];
            acc[mt] = __builtin_amdgcn_mfma_f32_16x16x32_f16(af, bf, acc[mt], 0, 0, 0);
        }
    }

    const int colw = wave * 16 + row16;
    const float arc = arn[colw];
    const int rg = (lane >> 4) * 4;
    const int head = colw >> 3;
    const int nb = blockIdx.x * 32;
#pragma unroll
    for (int mt = 0; mt < 2; mt++) {
#pragma unroll
        for (int j = 0; j < 4; j++) {
            int n2 = nb + mt * 16 + rg + j;
            float val = acc[mt][j];
            hbuf_out[(size_t)n2 * HD + colw] = __float2half(val);
            float p = val * arc;
            p += __shfl_xor(p, 1);
            p += __shfl_xor(p, 2);
            p += __shfl_xor(p, 4);
            if ((lane & 7) == 0) er_out[(size_t)n2 * 8 + head] = p;
        }
    }
}

// ---------------- final agg (layer 2): f32 output (unchanged) ----------------
__global__ __launch_bounds__(256) void agg_kernel(
    const __half* __restrict__ hbuf, const float* __restrict__ al,
    const float* __restrict__ er, const int* __restrict__ deg,
    const int* __restrict__ csr_pad, const float* __restrict__ bias,
    float* __restrict__ out) {
    const int wave = threadIdx.x >> 6;
    const int lane = threadIdx.x & 63;
    const int oct = blockIdx.x * 4 + wave;
    const int g = lane >> 3;
    const int q = lane & 7;
    const int node = oct * 8 + g;
    const int cnt = min(deg[node], CAP);
    const float erv = er[(size_t)node * 8 + q];
    int4 rv = *(const int4*)&csr_pad[(size_t)node * CAP + q * 4];

    float4 av0 = *(const float4*)&al[q * 8];
    float4 av1 = *(const float4*)&al[q * 8 + 4];
    float4 bv0 = *(const float4*)&bias[q * 8];
    float4 bv1 = *(const float4*)&bias[q * 8 + 4];
    int cmax = cnt;
    cmax = max(cmax, __shfl_xor(cmax, 8));
    cmax = max(cmax, __shfl_xor(cmax, 16));
    cmax = max(cmax, __shfl_xor(cmax, 32));
    const int cm = max(cnt - 1, 0);
    const int gbase = lane & 56;

    int scl;
    {
        int bl = gbase + (cm >> 2);
        int c0 = __shfl(rv.x, bl), c1 = __shfl(rv.y, bl);
        int c2 = __shfl(rv.z, bl), c3 = __shfl(rv.w, bl);
        int cc = cm & 3;
        scl = cc == 0 ? c0 : (cc == 1 ? c1 : (cc == 2 ? c2 : c3));
        scl = (unsigned)scl < NN ? scl : 0;
    }

    float4 a0 = make_float4(0.f, 0.f, 0.f, 0.f);
    float4 a1 = make_float4(0.f, 0.f, 0.f, 0.f);
    float ssum = 0.f;

    for (int jj = 0; jj < cmax; jj += 8) {
        const int b0 = gbase + (jj >> 2);
        int sl[8];
        sl[0] = __shfl(rv.x, b0);     sl[1] = __shfl(rv.y, b0);
        sl[2] = __shfl(rv.z, b0);     sl[3] = __shfl(rv.w, b0);
        sl[4] = __shfl(rv.x, b0 + 1); sl[5] = __shfl(rv.y, b0 + 1);
        sl[6] = __shfl(rv.z, b0 + 1); sl[7] = __shfl(rv.w, b0 + 1);
        bool v[8];
#pragma unroll
        for (int t = 0; t < 8; t++) {
            v[t] = (jj + t) < cnt;
            int s = v[t] ? sl[t] : scl;
            sl[t] = (unsigned)s < NN ? s : 0;
        }
        uint4 hh[8];
#pragma unroll
        for (int t = 0; t < 8; t++) hh[t] = *(const uint4*)&hbuf[(size_t)sl[t] * HD + q * 8];
#pragma unroll
        for (int t = 0; t < 8; t++) {
            float2 u0 = __half22float2(*(__half2*)&hh[t].x);
            float2 u1 = __half22float2(*(__half2*)&hh[t].y);
            float2 u2 = __half22float2(*(__half2*)&hh[t].z);
            float2 u3 = __half22float2(*(__half2*)&hh[t].w);
            float elv = u0.x * av0.x + u0.y * av0.y + u1.x * av0.z + u1.y * av0.w
                      + u2.x * av1.x + u2.y * av1.y + u3.x * av1.z + u3.y * av1.w;
            float tt = elv + erv;
            tt = tt > 0.f ? tt : 0.2f * tt;
            float p = v[t] ? __expf(tt) : 0.f;
            ssum += p;
            a0.x = fmaf(p, u0.x, a0.x); a0.y = fmaf(p, u0.y, a0.y);
            a0.z = fmaf(p, u1.x, a0.z); a0.w = fmaf(p, u1.y, a0.w);
            a1.x = fmaf(p, u2.x, a1.x); a1.y = fmaf(p, u2.y, a1.y);
            a1.z = fmaf(p, u3.x, a1.z); a1.w = fmaf(p, u3.y, a1.w);
        }
    }

    float inv = ssum > 0.f ? 1.f / ssum : 0.f;
    float4 o0, o1;
    o0.x = fmaf(a0.x, inv, bv0.x); o0.y = fmaf(a0.y, inv, bv0.y);
    o0.z = fmaf(a0.z, inv, bv0.z); o0.w = fmaf(a0.w, inv, bv0.w);
    o1.x = fmaf(a1.x, inv, bv1.x); o1.y = fmaf(a1.y, inv, bv1.y);
    o1.z = fmaf(a1.z, inv, bv1.z); o1.w = fmaf(a1.w, inv, bv1.w);
    *(float4*)&out[(size_t)node * HD + q * 8] = o0;
    *(float4*)&out[(size_t)node * HD + q * 8 + 4] = o1;
}

// ---------------- launch ----------------

static inline size_t al512(size_t x) { return (x + 511) & ~(size_t)511; }

extern "C" void kernel_launch(void* const* d_in, const int* in_sizes, int n_in,
                              void* d_out, int out_size, void* d_ws, size_t ws_size,
                              hipStream_t stream) {
    const float* n_feat = (const float*)d_in[0];
    const int* src = (const int*)d_in[2];
    const int* dst = (const int*)d_in[3];
    const float* W[3]  = {(const float*)d_in[4], (const float*)d_in[8],  (const float*)d_in[12]};
    const float* al[3] = {(const float*)d_in[5], (const float*)d_in[9],  (const float*)d_in[13]};
    const float* ar[3] = {(const float*)d_in[6], (const float*)d_in[10], (const float*)d_in[14]};
    const float* bs[3] = {(const float*)d_in[7], (const float*)d_in[11], (const float*)d_in[15]};
    float* outF = (float*)d_out;

    char* ws = (char*)d_ws;
    size_t off = 0;
    int* deg     = (int*)(ws + off); off += (size_t)NN * 4;
    int* cursor  = (int*)(ws + off); off += al512((size_t)NBUK * 4);
    int* csr_pad = (int*)(ws + off); off += al512((size_t)NN * CAP * 4);
    int2* bbuf   = (int2*)(ws + off); off += al512((size_t)NBUK * BCAP * 8);
    __half* hA   = (__half*)(ws + off); off += al512((size_t)NN * HD * 2);
    __half* hB   = (__half*)(ws + off); off += al512((size_t)NN * HD * 2);
    float* erA   = (float*)(ws + off); off += al512((size_t)NN * 8 * 4);
    float* erB   = (float*)(ws + off); off += al512((size_t)NN * 8 * 4);

    // only bucket cursors need zeroing now (deg written non-atomically by build2)
    hipMemsetAsync(cursor, 0, (size_t)NBUK * 4, stream);
    bucket_kernel<<<P1_BLOCKS, 256, 0, stream>>>(src, dst, cursor, bbuf);
    build2_kernel<<<NBUK, 512, 0, stream>>>(cursor, bbuf, deg, csr_pad);
    lin_mfma<<<LINB, 256, 0, stream>>>(n_feat, W[0], ar[0], hA, erA);
    agg_lin_kernel<true><<<AGGB, 256, 0, stream>>>(hA, al[0], erA, deg, csr_pad, bs[0],
                                                   W[1], ar[1], hB, erB);
    agg_lin_kernel<true><<<AGGB, 256, 0, stream>>>(hB, al[1], erB, deg, csr_pad, bs[1],
                                                   W[2], ar[2], hA, erA);
    agg_kernel<<<AGGB, 256, 0, stream>>>(hA, al[2], erA, deg, csr_pad, bs[2], outF);
}

// Round 16
// 132.754 us; speedup vs baseline: 1.4984x; 1.0269x over previous
//
#include <hip/hip_runtime.h>
#include <hip/hip_fp16.h>
#include <math.h>

#define NN 100000
#define NE 800000
#define HH 8
#define DD 8
#define HD 64
#define CAP 32      // padded CSR row capacity; deg ~ Poisson(8), overflow negligible (validated R3-R15)

#define NBUK 200    // dst-range buckets (500 nodes each; NN = NBUK*BNODES exactly)
#define BNODES 500
#define BCAP 4400
#define P1_EPB 1024
#define P1_BLOCKS ((NE + P1_EPB - 1) / P1_EPB)   // 782

#define NOCT (NN / 8)        // 12500 octets, exact
#define AGGB (NOCT / 4)      // 3125 blocks x 4 waves (32 nodes/block)
#define LINB ((NN + 63) / 64)                    // 1563

typedef _Float16 half8_t __attribute__((ext_vector_type(8)));
typedef float f32x4_t __attribute__((ext_vector_type(4)));

// ---------------- fused pass1 (edge bucketing) + lin0 (MFMA GEMM) ----------------
// R16: bucket and lin0 are mutually independent (src/dst -> cursor/bbuf vs
// n_feat/W0 -> hA/erA); co-scheduling hides bucket's ~6us under lin0's ~12us
// and removes one dispatch boundary. Bucket branch reuses the lin LDS block
// for its 1.6KB hist (no extra LDS). Both products consumed later (build2 /
// agg_lin0).
__global__ __launch_bounds__(256) void bucket_lin_kernel(
    const int* __restrict__ src, const int* __restrict__ dst,
    int* __restrict__ cursor, int2* __restrict__ bbuf,
    const float* __restrict__ x, const float* __restrict__ W,
    const float* __restrict__ ar, __half* __restrict__ h, float* __restrict__ er) {
    constexpr int K = 128, KP = K + 8;
    __shared__ _Float16 xh[64][KP];
    __shared__ _Float16 wt[64][KP];
    const int tid = threadIdx.x;

    if (blockIdx.x < P1_BLOCKS) {
        // ---- bucket branch (reuses xh storage for int hist/base) ----
        int* hist = (int*)&xh[0][0];
        int* base = hist + NBUK;
        for (int i = tid; i < NBUK; i += 256) hist[i] = 0;
        __syncthreads();
        const int e0 = blockIdx.x * P1_EPB;
        int myb[4], myrank[4], mysrc[4], mydst[4];
#pragma unroll
        for (int i = 0; i < 4; i++) {
            int e = e0 + tid + i * 256;
            bool v = e < NE;
            int d = v ? dst[e] : 0;
            int b = d / BNODES;
            myb[i] = b;
            mydst[i] = d;
            mysrc[i] = v ? src[e] : 0;
            myrank[i] = v ? atomicAdd(&hist[b], 1) : -1;
        }
        __syncthreads();
        for (int i = tid; i < NBUK; i += 256) {
            int c = hist[i];
            base[i] = c > 0 ? atomicAdd(&cursor[i], c) : 0;
        }
        __syncthreads();
#pragma unroll
        for (int i = 0; i < 4; i++) {
            if (myrank[i] >= 0) {
                int pos = base[myb[i]] + myrank[i];
                if (pos < BCAP) bbuf[(size_t)myb[i] * BCAP + pos] = make_int2(mysrc[i], mydst[i]);
            }
        }
        return;
    }

    // ---- lin0 branch (R15 lin_mfma, conflict-free wt staging) ----
    const int w = tid >> 6;
    const int l = tid & 63;
    const int nb = (blockIdx.x - P1_BLOCKS) * 64;

#pragma unroll
    for (int it = 0; it < 8; it++) {
        int idx = tid + it * 256;
        int r = idx / (K / 4);
        int c4 = idx % (K / 4);
        int node = nb + r; if (node >= NN) node = NN - 1;
        float4 v = *(const float4*)&x[(size_t)node * K + c4 * 4];
        union { _Float16 f[4]; uint2 u; } pk;
        pk.f[0] = (_Float16)v.x; pk.f[1] = (_Float16)v.y;
        pk.f[2] = (_Float16)v.z; pk.f[3] = (_Float16)v.w;
        *(uint2*)&xh[r][c4 * 4] = pk.u;
    }
    // W^T staging: lane owns (col c, 4 consecutive k) -> conflict-free
#pragma unroll
    for (int it = 0; it < 8; it++) {
        int idx = tid + it * 256;
        int c = idx & 63;
        int k4 = idx >> 6;
        union { _Float16 f[4]; uint2 u; } pk;
        pk.f[0] = (_Float16)W[(size_t)(k4 * 4 + 0) * 64 + c];
        pk.f[1] = (_Float16)W[(size_t)(k4 * 4 + 1) * 64 + c];
        pk.f[2] = (_Float16)W[(size_t)(k4 * 4 + 2) * 64 + c];
        pk.f[3] = (_Float16)W[(size_t)(k4 * 4 + 3) * 64 + c];
        *(uint2*)&wt[c][k4 * 4] = pk.u;
    }
    __syncthreads();

    const int row16 = l & 15;
    const int kgrp = (l >> 4) * 8;
    f32x4_t acc[4];
#pragma unroll
    for (int r = 0; r < 4; r++) acc[r] = (f32x4_t){0.f, 0.f, 0.f, 0.f};

#pragma unroll
    for (int k0 = 0; k0 < K; k0 += 32) {
        half8_t bf = *(const half8_t*)&wt[w * 16 + row16][k0 + kgrp];
#pragma unroll
        for (int r = 0; r < 4; r++) {
            half8_t af = *(const half8_t*)&xh[r * 16 + row16][k0 + kgrp];
            acc[r] = __builtin_amdgcn_mfma_f32_16x16x32_f16(af, bf, acc[r], 0, 0, 0);
        }
    }

    const int colw = w * 16 + row16;
    const float arc = ar[colw];
    const int rg = (l >> 4) * 4;
    const int head = colw >> 3;
#pragma unroll
    for (int r = 0; r < 4; r++) {
#pragma unroll
        for (int j = 0; j < 4; j++) {
            int node = nb + r * 16 + rg + j;
            float val = acc[r][j];
            if (node < NN) h[(size_t)node * HD + colw] = __float2half(val);
            float p = val * arc;
            p += __shfl_xor(p, 1);
            p += __shfl_xor(p, 2);
            p += __shfl_xor(p, 4);
            if ((l & 7) == 0 && node < NN) er[(size_t)node * 8 + head] = p;
        }
    }
}

// ---------------- pass2: per-bucket COUNTING SORT -> deg + padded CSR ----------------
__global__ __launch_bounds__(512) void build2_kernel(const int* __restrict__ cursor,
                                                     const int2* __restrict__ bbuf,
                                                     int* __restrict__ deg,
                                                     int* __restrict__ csr_pad) {
    __shared__ int hist[512];
    __shared__ int base[512];
    __shared__ int cur[512];
    __shared__ int wsum[8];
    const int tid = threadIdx.x;
    const int wid = tid >> 6;
    const int lane = tid & 63;
    const int b = blockIdx.x;
    const int node0 = b * BNODES;
    const int cnt = min(cursor[b], BCAP);
    const int2* bb = bbuf + (size_t)b * BCAP;

    hist[tid] = 0;
    __syncthreads();
    for (int i = tid; i < cnt; i += 512) {
        int d = bb[i].y - node0;
        atomicAdd(&hist[d], 1);
    }
    __syncthreads();
    int v = hist[tid];
    if (tid < BNODES) deg[node0 + tid] = v;     // coalesced, non-atomic
    int inc = v;
    for (int off = 1; off < 64; off <<= 1) {
        int t = __shfl_up(inc, off);
        if (lane >= off) inc += t;
    }
    if (lane == 63) wsum[wid] = inc;
    __syncthreads();
    if (wid == 0) {
        int s = (lane < 8) ? wsum[lane] : 0;
        int si = s;
        for (int off = 1; off < 8; off <<= 1) {
            int t = __shfl_up(si, off);
            if (lane >= off) si += t;
        }
        if (lane < 8) wsum[lane] = si - s;
    }
    __syncthreads();
    int excl = inc - v + wsum[wid];
    base[tid] = excl;
    cur[tid] = excl;
    __syncthreads();
    for (int i = tid; i < cnt; i += 512) {
        int2 p = bb[i];
        int d = p.y - node0;
        int pos = atomicAdd(&cur[d], 1);        // LDS atomic
        int slot = pos - base[d];
        if (slot < CAP) csr_pad[(size_t)p.y * CAP + slot] = p.x;
    }
}

// ---------------- fused agg + next-layer lin (unchanged from R15) ----------------
template <bool ACT>
__global__ __launch_bounds__(256) void agg_lin_kernel(
    const __half* __restrict__ hbuf_in, const float* __restrict__ al,
    const float* __restrict__ er_in, const int* __restrict__ deg,
    const int* __restrict__ csr_pad, const float* __restrict__ bias,
    const float* __restrict__ Wn, const float* __restrict__ arn,
    __half* __restrict__ hbuf_out, float* __restrict__ er_out) {
    __shared__ _Float16 wt[64][72];   // W_next transposed, fp16
    __shared__ _Float16 xs[32][88];   // this block's 32 output rows, fp16
    const int tid = threadIdx.x;
    const int wave = tid >> 6;
    const int lane = tid & 63;
    const int oct = blockIdx.x * 4 + wave;
    const int g = lane >> 3;
    const int q = lane & 7;
    const int node = oct * 8 + g;

#pragma unroll
    for (int it = 0; it < 4; it++) {
        int idx = tid + it * 256;
        int c = idx & 63;
        int k4 = idx >> 6;
        union { _Float16 f[4]; uint2 u; } pk;
        pk.f[0] = (_Float16)Wn[(size_t)(k4 * 4 + 0) * 64 + c];
        pk.f[1] = (_Float16)Wn[(size_t)(k4 * 4 + 1) * 64 + c];
        pk.f[2] = (_Float16)Wn[(size_t)(k4 * 4 + 2) * 64 + c];
        pk.f[3] = (_Float16)Wn[(size_t)(k4 * 4 + 3) * 64 + c];
        *(uint2*)&wt[c][k4 * 4] = pk.u;
    }

    const int cnt = min(deg[node], CAP);
    const float erv = er_in[(size_t)node * 8 + q];
    int4 rv = *(const int4*)&csr_pad[(size_t)node * CAP + q * 4];

    float4 av0 = *(const float4*)&al[q * 8];
    float4 av1 = *(const float4*)&al[q * 8 + 4];
    float4 bv0 = *(const float4*)&bias[q * 8];
    float4 bv1 = *(const float4*)&bias[q * 8 + 4];
    int cmax = cnt;
    cmax = max(cmax, __shfl_xor(cmax, 8));
    cmax = max(cmax, __shfl_xor(cmax, 16));
    cmax = max(cmax, __shfl_xor(cmax, 32));
    const int cm = max(cnt - 1, 0);
    const int gbase = lane & 56;

    int scl;
    {
        int bl = gbase + (cm >> 2);
        int c0 = __shfl(rv.x, bl), c1 = __shfl(rv.y, bl);
        int c2 = __shfl(rv.z, bl), c3 = __shfl(rv.w, bl);
        int cc = cm & 3;
        scl = cc == 0 ? c0 : (cc == 1 ? c1 : (cc == 2 ? c2 : c3));
        scl = (unsigned)scl < NN ? scl : 0;
    }

    float4 a0 = make_float4(0.f, 0.f, 0.f, 0.f);
    float4 a1 = make_float4(0.f, 0.f, 0.f, 0.f);
    float ssum = 0.f;

    for (int jj = 0; jj < cmax; jj += 8) {
        const int b0 = gbase + (jj >> 2);
        int sl[8];
        sl[0] = __shfl(rv.x, b0);     sl[1] = __shfl(rv.y, b0);
        sl[2] = __shfl(rv.z, b0);     sl[3] = __shfl(rv.w, b0);
        sl[4] = __shfl(rv.x, b0 + 1); sl[5] = __shfl(rv.y, b0 + 1);
        sl[6] = __shfl(rv.z, b0 + 1); sl[7] = __shfl(rv.w, b0 + 1);
        bool v[8];
#pragma unroll
        for (int t = 0; t < 8; t++) {
            v[t] = (jj + t) < cnt;
            int s = v[t] ? sl[t] : scl;
            sl[t] = (unsigned)s < NN ? s : 0;
        }
        uint4 hh[8];
#pragma unroll
        for (int t = 0; t < 8; t++) hh[t] = *(const uint4*)&hbuf_in[(size_t)sl[t] * HD + q * 8];
#pragma unroll
        for (int t = 0; t < 8; t++) {
            float2 u0 = __half22float2(*(__half2*)&hh[t].x);
            float2 u1 = __half22float2(*(__half2*)&hh[t].y);
            float2 u2 = __half22float2(*(__half2*)&hh[t].z);
            float2 u3 = __half22float2(*(__half2*)&hh[t].w);
            float elv = u0.x * av0.x + u0.y * av0.y + u1.x * av0.z + u1.y * av0.w
                      + u2.x * av1.x + u2.y * av1.y + u3.x * av1.z + u3.y * av1.w;
            float tt = elv + erv;
            tt = tt > 0.f ? tt : 0.2f * tt;
            float p = v[t] ? __expf(tt) : 0.f;
            ssum += p;
            a0.x = fmaf(p, u0.x, a0.x); a0.y = fmaf(p, u0.y, a0.y);
            a0.z = fmaf(p, u1.x, a0.z); a0.w = fmaf(p, u1.y, a0.w);
            a1.x = fmaf(p, u2.x, a1.x); a1.y = fmaf(p, u2.y, a1.y);
            a1.z = fmaf(p, u3.x, a1.z); a1.w = fmaf(p, u3.y, a1.w);
        }
    }

    float inv = ssum > 0.f ? 1.f / ssum : 0.f;
    float o0x = fmaf(a0.x, inv, bv0.x), o0y = fmaf(a0.y, inv, bv0.y);
    float o0z = fmaf(a0.z, inv, bv0.z), o0w = fmaf(a0.w, inv, bv0.w);
    float o1x = fmaf(a1.x, inv, bv1.x), o1y = fmaf(a1.y, inv, bv1.y);
    float o1z = fmaf(a1.z, inv, bv1.z), o1w = fmaf(a1.w, inv, bv1.w);
    if (ACT) {
        o0x = o0x > 0.f ? o0x : 0.01f * o0x;
        o0y = o0y > 0.f ? o0y : 0.01f * o0y;
        o0z = o0z > 0.f ? o0z : 0.01f * o0z;
        o0w = o0w > 0.f ? o0w : 0.01f * o0w;
        o1x = o1x > 0.f ? o1x : 0.01f * o1x;
        o1y = o1y > 0.f ? o1y : 0.01f * o1y;
        o1z = o1z > 0.f ? o1z : 0.01f * o1z;
        o1w = o1w > 0.f ? o1w : 0.01f * o1w;
    }
    {
        union { _Float16 f[8]; uint4 u; } pk;
        pk.f[0] = (_Float16)o0x; pk.f[1] = (_Float16)o0y;
        pk.f[2] = (_Float16)o0z; pk.f[3] = (_Float16)o0w;
        pk.f[4] = (_Float16)o1x; pk.f[5] = (_Float16)o1y;
        pk.f[6] = (_Float16)o1z; pk.f[7] = (_Float16)o1w;
        *(uint4*)&xs[wave * 8 + g][q * 8] = pk.u;
    }
    __syncthreads();

    const int row16 = lane & 15;
    const int kgrp = (lane >> 4) * 8;
    f32x4_t acc[2];
    acc[0] = (f32x4_t){0.f, 0.f, 0.f, 0.f};
    acc[1] = (f32x4_t){0.f, 0.f, 0.f, 0.f};
#pragma unroll
    for (int k0 = 0; k0 < 64; k0 += 32) {
        half8_t bf = *(const half8_t*)&wt[wave * 16 + row16][k0 + kgrp];
#pragma unroll
        for (int mt = 0; mt < 2; mt++) {
            half8_t af = *(const half8_t*)&xs[mt * 16 + row16][k0 + kgrp];
            acc[mt] = __builtin_amdgcn_mfma_f32_16x16x32_f16(af, bf, acc[mt], 0, 0, 0);
        }
    }

    const int colw = wave * 16 + row16;
    const float arc = arn[colw];
    const int rg = (lane >> 4) * 4;
    const int head = colw >> 3;
    const int nb = blockIdx.x * 32;
#pragma unroll
    for (int mt = 0; mt < 2; mt++) {
#pragma unroll
        for (int j = 0; j < 4; j++) {
            int n2 = nb + mt * 16 + rg + j;
            float val = acc[mt][j];
            hbuf_out[(size_t)n2 * HD + colw] = __float2half(val);
            float p = val * arc;
            p += __shfl_xor(p, 1);
            p += __shfl_xor(p, 2);
            p += __shfl_xor(p, 4);
            if ((lane & 7) == 0) er_out[(size_t)n2 * 8 + head] = p;
        }
    }
}

// ---------------- final agg (layer 2): f32 output (unchanged) ----------------
__global__ __launch_bounds__(256) void agg_kernel(
    const __half* __restrict__ hbuf, const float* __restrict__ al,
    const float* __restrict__ er, const int* __restrict__ deg,
    const int* __restrict__ csr_pad, const float* __restrict__ bias,
    float* __restrict__ out) {
    const int wave = threadIdx.x >> 6;
    const int lane = threadIdx.x & 63;
    const int oct = blockIdx.x * 4 + wave;
    const int g = lane >> 3;
    const int q = lane & 7;
    const int node = oct * 8 + g;
    const int cnt = min(deg[node], CAP);
    const float erv = er[(size_t)node * 8 + q];
    int4 rv = *(const int4*)&csr_pad[(size_t)node * CAP + q * 4];

    float4 av0 = *(const float4*)&al[q * 8];
    float4 av1 = *(const float4*)&al[q * 8 + 4];
    float4 bv0 = *(const float4*)&bias[q * 8];
    float4 bv1 = *(const float4*)&bias[q * 8 + 4];
    int cmax = cnt;
    cmax = max(cmax, __shfl_xor(cmax, 8));
    cmax = max(cmax, __shfl_xor(cmax, 16));
    cmax = max(cmax, __shfl_xor(cmax, 32));
    const int cm = max(cnt - 1, 0);
    const int gbase = lane & 56;

    int scl;
    {
        int bl = gbase + (cm >> 2);
        int c0 = __shfl(rv.x, bl), c1 = __shfl(rv.y, bl);
        int c2 = __shfl(rv.z, bl), c3 = __shfl(rv.w, bl);
        int cc = cm & 3;
        scl = cc == 0 ? c0 : (cc == 1 ? c1 : (cc == 2 ? c2 : c3));
        scl = (unsigned)scl < NN ? scl : 0;
    }

    float4 a0 = make_float4(0.f, 0.f, 0.f, 0.f);
    float4 a1 = make_float4(0.f, 0.f, 0.f, 0.f);
    float ssum = 0.f;

    for (int jj = 0; jj < cmax; jj += 8) {
        const int b0 = gbase + (jj >> 2);
        int sl[8];
        sl[0] = __shfl(rv.x, b0);     sl[1] = __shfl(rv.y, b0);
        sl[2] = __shfl(rv.z, b0);     sl[3] = __shfl(rv.w, b0);
        sl[4] = __shfl(rv.x, b0 + 1); sl[5] = __shfl(rv.y, b0 + 1);
        sl[6] = __shfl(rv.z, b0 + 1); sl[7] = __shfl(rv.w, b0 + 1);
        bool v[8];
#pragma unroll
        for (int t = 0; t < 8; t++) {
            v[t] = (jj + t) < cnt;
            int s = v[t] ? sl[t] : scl;
            sl[t] = (unsigned)s < NN ? s : 0;
        }
        uint4 hh[8];
#pragma unroll
        for (int t = 0; t < 8; t++) hh[t] = *(const uint4*)&hbuf[(size_t)sl[t] * HD + q * 8];
#pragma unroll
        for (int t = 0; t < 8; t++) {
            float2 u0 = __half22float2(*(__half2*)&hh[t].x);
            float2 u1 = __half22float2(*(__half2*)&hh[t].y);
            float2 u2 = __half22float2(*(__half2*)&hh[t].z);
            float2 u3 = __half22float2(*(__half2*)&hh[t].w);
            float elv = u0.x * av0.x + u0.y * av0.y + u1.x * av0.z + u1.y * av0.w
                      + u2.x * av1.x + u2.y * av1.y + u3.x * av1.z + u3.y * av1.w;
            float tt = elv + erv;
            tt = tt > 0.f ? tt : 0.2f * tt;
            float p = v[t] ? __expf(tt) : 0.f;
            ssum += p;
            a0.x = fmaf(p, u0.x, a0.x); a0.y = fmaf(p, u0.y, a0.y);
            a0.z = fmaf(p, u1.x, a0.z); a0.w = fmaf(p, u1.y, a0.w);
            a1.x = fmaf(p, u2.x, a1.x); a1.y = fmaf(p, u2.y, a1.y);
            a1.z = fmaf(p, u3.x, a1.z); a1.w = fmaf(p, u3.y, a1.w);
        }
    }

    float inv = ssum > 0.f ? 1.f / ssum : 0.f;
    float4 o0, o1;
    o0.x = fmaf(a0.x, inv, bv0.x); o0.y = fmaf(a0.y, inv, bv0.y);
    o0.z = fmaf(a0.z, inv, bv0.z); o0.w = fmaf(a0.w, inv, bv0.w);
    o1.x = fmaf(a1.x, inv, bv1.x); o1.y = fmaf(a1.y, inv, bv1.y);
    o1.z = fmaf(a1.z, inv, bv1.z); o1.w = fmaf(a1.w, inv, bv1.w);
    *(float4*)&out[(size_t)node * HD + q * 8] = o0;
    *(float4*)&out[(size_t)node * HD + q * 8 + 4] = o1;
}

// ---------------- launch ----------------

static inline size_t al512(size_t x) { return (x + 511) & ~(size_t)511; }

extern "C" void kernel_launch(void* const* d_in, const int* in_sizes, int n_in,
                              void* d_out, int out_size, void* d_ws, size_t ws_size,
                              hipStream_t stream) {
    const float* n_feat = (const float*)d_in[0];
    const int* src = (const int*)d_in[2];
    const int* dst = (const int*)d_in[3];
    const float* W[3]  = {(const float*)d_in[4], (const float*)d_in[8],  (const float*)d_in[12]};
    const float* al[3] = {(const float*)d_in[5], (const float*)d_in[9],  (const float*)d_in[13]};
    const float* ar[3] = {(const float*)d_in[6], (const float*)d_in[10], (const float*)d_in[14]};
    const float* bs[3] = {(const float*)d_in[7], (const float*)d_in[11], (const float*)d_in[15]};
    float* outF = (float*)d_out;

    char* ws = (char*)d_ws;
    size_t off = 0;
    int* deg     = (int*)(ws + off); off += (size_t)NN * 4;
    int* cursor  = (int*)(ws + off); off += al512((size_t)NBUK * 4);
    int* csr_pad = (int*)(ws + off); off += al512((size_t)NN * CAP * 4);
    int2* bbuf   = (int2*)(ws + off); off += al512((size_t)NBUK * BCAP * 8);
    __half* hA   = (__half*)(ws + off); off += al512((size_t)NN * HD * 2);
    __half* hB   = (__half*)(ws + off); off += al512((size_t)NN * HD * 2);
    float* erA   = (float*)(ws + off); off += al512((size_t)NN * 8 * 4);
    float* erB   = (float*)(ws + off); off += al512((size_t)NN * 8 * 4);

    hipMemsetAsync(cursor, 0, (size_t)NBUK * 4, stream);
    bucket_lin_kernel<<<P1_BLOCKS + LINB, 256, 0, stream>>>(src, dst, cursor, bbuf,
                                                            n_feat, W[0], ar[0], hA, erA);
    build2_kernel<<<NBUK, 512, 0, stream>>>(cursor, bbuf, deg, csr_pad);
    agg_lin_kernel<true><<<AGGB, 256, 0, stream>>>(hA, al[0], erA, deg, csr_pad, bs[0],
                                                   W[1], ar[1], hB, erB);
    agg_lin_kernel<true><<<AGGB, 256, 0, stream>>>(hB, al[1], erB, deg, csr_pad, bs[1],
                                                   W[2], ar[2], hA, erA);
    agg_kernel<<<AGGB, 256, 0, stream>>>(hA, al[2], erA, deg, csr_pad, bs[2], outF);
}